// Round 4
// baseline (997.244 us; speedup 1.0000x reference)
//
#include <hip/hip_runtime.h>
#include <hip/hip_cooperative_groups.h>
#include <cstdint>
#include <cstddef>

namespace cg = cooperative_groups;

#define NN 100000
#define NP 100096          // rows padded to multiple of 64
#define EE 1600000
#define ET 1700000         // EE + NN self-loops
#define NBKT 196           // ceil(NN/512) dst-range buckets
#define TILE 2048          // edges per bucket-phase block
#define BUILD_GRID 831     // ceil(ET/TILE); co-resident (34KB LDS -> 4 blk/CU -> 1024 max)
#define STAT_BLOCKS 400

typedef short  bf16x8 __attribute__((ext_vector_type(8)));
typedef float  f32x4  __attribute__((ext_vector_type(4)));

__device__ __forceinline__ unsigned short f2bf(float f) {
    unsigned int x = __builtin_bit_cast(unsigned int, f);
    x += 0x7FFFu + ((x >> 16) & 1u);   // RNE
    return (unsigned short)(x >> 16);
}
__device__ __forceinline__ unsigned int pk2(float lo, float hi) {
    return ((unsigned int)f2bf(hi) << 16) | (unsigned int)f2bf(lo);
}
__device__ __forceinline__ float bflo(unsigned int u) {
    return __builtin_bit_cast(float, u << 16);
}
__device__ __forceinline__ float bfhi(unsigned int u) {
    return __builtin_bit_cast(float, u & 0xFFFF0000u);
}

// =================== fused CSR build + weight cvt (ONE cooperative dispatch) ===================
// bucket = dst >> 9 (512 dsts per bucket); packed edge = (dst&511)<<17 | src
// P0 zero+cvtw | P1 count | P2 scan(blk0) | P3 rank+scatter | P4 per-bucket CSR
__global__ __launch_bounds__(256, 4) void k_build(
    const int* __restrict__ ei,
    const float* __restrict__ W0, const float* __restrict__ W1, const float* __restrict__ W2,
    unsigned short* __restrict__ Wb,
    int* __restrict__ btot, int* __restrict__ bstart, int* __restrict__ bcur,
    int* __restrict__ off, unsigned int* __restrict__ bucketed, int* __restrict__ srcs,
    float* __restrict__ gstat)
{
    __shared__ int h4[4][256], woff[4][256], loff[256], gbase[256], sc[256];
    __shared__ unsigned int stage[TILE];
    __shared__ int gaddr[TILE];
    __shared__ int stot_s;
    __shared__ int hh[512], sc2[512], c2[512], sp[256];

    const int t = threadIdx.x;
    const int b = blockIdx.x;
    const int w = t >> 6;
    cg::grid_group grid = cg::this_grid();

    // ---------- P0: zero counters/stats + weight conversion ----------
    if (b == 0) btot[t] = 0;
    if (b == 1) { gstat[t] = 0.f; gstat[t + 256] = 0.f; }
    for (int i = b * 256 + t; i < 3 * 16384; i += BUILD_GRID * 256) {
        const float* W = (i < 16384) ? W0 : (i < 32768) ? W1 : W2;
        Wb[i] = f2bf(W[i & 16383]);
    }
    grid.sync();

    // ---------- P1: bucket counts ----------
    hh[t] = 0; hh[t + 256] = 0;
    __syncthreads();
    for (int e = b * 256 + t; e < ET; e += BUILD_GRID * 256) {
        int d = (e < EE) ? ei[EE + e] : (e - EE);
        atomicAdd(&hh[d >> 9], 1);
    }
    __syncthreads();
    if (hh[t]) atomicAdd(&btot[t], hh[t]);
    grid.sync();

    // ---------- P2: bucket scan (block 0 only) ----------
    if (b == 0) {
        int v = (t < NBKT) ? btot[t] : 0;
        sp[t] = v;
        __syncthreads();
        for (int o = 1; o < 256; o <<= 1) {
            int a = (t >= o) ? sp[t - o] : 0;
            __syncthreads();
            sp[t] += a;
            __syncthreads();
        }
        int ex = sp[t] - v;
        if (t < NBKT) bstart[t] = ex;
        if (t == NBKT - 1) bstart[NBKT] = sp[t];   // == ET
        bcur[t] = ex;
        if (t == 0) off[NN] = ET;
    }
    grid.sync();

    // ---------- P3: rank + scatter into buckets ----------
    {
        const int e0 = b * TILE;
        h4[0][t] = 0; h4[1][t] = 0; h4[2][t] = 0; h4[3][t] = 0;
        __syncthreads();

        unsigned int pk[TILE / 256];
        int bk[TILE / 256];
#pragma unroll
        for (int i = 0; i < TILE / 256; ++i) {
            int e = e0 + i * 256 + t;
            bk[i] = -1;
            if (e < ET) {
                int s, d;
                if (e < EE) { s = ei[e]; d = ei[EE + e]; } else { s = e - EE; d = s; }
                bk[i] = d >> 9;
                pk[i] = ((unsigned int)(d & 511) << 17) | (unsigned int)s;
                atomicAdd(&h4[w][bk[i]], 1);
            }
        }
        __syncthreads();

        int h0 = h4[0][t], h1 = h4[1][t], h2 = h4[2][t], h3 = h4[3][t];
        int tot = h0 + h1 + h2 + h3;
        sc[t] = tot;
        __syncthreads();
        for (int o = 1; o < 256; o <<= 1) {
            int a = (t >= o) ? sc[t - o] : 0;
            __syncthreads();
            sc[t] += a;
            __syncthreads();
        }
        int lo = sc[t] - tot;
        loff[t] = lo;
        woff[0][t] = lo;
        woff[1][t] = lo + h0;
        woff[2][t] = lo + h0 + h1;
        woff[3][t] = lo + h0 + h1 + h2;
        if (t < NBKT && tot) gbase[t] = atomicAdd(&bcur[t], tot);
        if (t == 255) stot_s = sc[255];
        h4[0][t] = 0; h4[1][t] = 0; h4[2][t] = 0; h4[3][t] = 0;
        __syncthreads();

#pragma unroll
        for (int i = 0; i < TILE / 256; ++i) {
            if (bk[i] >= 0) {
                int bb = bk[i];
                int r = woff[w][bb] + atomicAdd(&h4[w][bb], 1);
                stage[r] = pk[i];
                gaddr[r] = gbase[bb] + (r - loff[bb]);
            }
        }
        __syncthreads();

        const int stot = stot_s;
        for (int j = t; j < stot; j += 256)
            bucketed[gaddr[j]] = stage[j];
    }
    grid.sync();

    // ---------- P4: per-bucket CSR (first NBKT blocks) ----------
    if (b < NBKT) {
        const int beg = bstart[b], end = bstart[b + 1];
        const int cnt = end - beg;

        hh[t] = 0; hh[t + 256] = 0; c2[t] = 0; c2[t + 256] = 0;
        __syncthreads();
        for (int i = t; i < cnt; i += 256)
            atomicAdd(&hh[bucketed[beg + i] >> 17], 1);
        __syncthreads();

        int a0 = hh[2 * t], a1 = hh[2 * t + 1];
        sp[t] = a0 + a1;
        __syncthreads();
        for (int o = 1; o < 256; o <<= 1) {
            int a = (t >= o) ? sp[t - o] : 0;
            __syncthreads();
            sp[t] += a;
            __syncthreads();
        }
        int ep = sp[t] - (a0 + a1);
        sc2[2 * t] = ep;
        sc2[2 * t + 1] = ep + a0;
        __syncthreads();

        const int d0 = b << 9;
#pragma unroll
        for (int k = t; k < 512; k += 256) {
            int d = d0 + k;
            if (d < NN) off[d] = beg + sc2[k];
        }

        for (int i = t; i < cnt; i += 256) {
            unsigned int v = bucketed[beg + i];
            int ld = v >> 17;
            int r = atomicAdd(&c2[ld], 1);
            srcs[beg + sc2[ld] + r] = (int)(v & 0x1FFFFu);
        }
    }
}

// ======================= MFMA GEMM: H = X @ W^T, fused BN-affine/relu/cvt + AS/AD ===========
// MODE 0: fp32 X read (layer 0); MODE 1: bf16 X read + BN affine (from raw stats) + relu
template<int MODE>
__global__ __launch_bounds__(256) void k_mfma(
    const void* __restrict__ Xv, const unsigned short* __restrict__ Wb,
    const float* __restrict__ gsum, const float* __restrict__ gsq,
    const float* __restrict__ gamma, const float* __restrict__ beta,
    const float* __restrict__ asrc, const float* __restrict__ adst,
    unsigned short* __restrict__ Hb, float* __restrict__ AS, float* __restrict__ AD)
{
    __shared__ float hst[4][16][132];
    __shared__ float scale_s[128], shift_s[128];
    const int t    = threadIdx.x;
    const int w    = t >> 6;
    const int lane = t & 63;
    const int c    = lane & 15;
    const int q    = lane >> 4;
    const int r0   = blockIdx.x * 64 + w * 16;
    const int row  = r0 + c;

    if (MODE) {
        // BN final stage fused here: per-column affine from raw sums (once per block)
        if (t < 128) {
            float mu  = gsum[t] * (1.f / NN);
            float var = gsq[t] * (1.f / NN) - mu * mu;
            float sc  = gamma[t] * rsqrtf(var + 1e-5f);
            scale_s[t] = sc;
            shift_s[t] = beta[t] - mu * sc;
        }
        __syncthreads();
    }

    union { uint4 u; bf16x8 v; } Af[4];
    if (row < NN) {
        if (MODE) {
            const unsigned short* xp = (const unsigned short*)Xv + ((size_t)row << 7) + (q << 3);
#pragma unroll
            for (int k0 = 0; k0 < 4; ++k0) {
                uint4 r = *(const uint4*)(xp + (k0 << 5));
                const int kb = (k0 << 5) + (q << 3);
                float a0 = bflo(r.x), a1 = bfhi(r.x), a2 = bflo(r.y), a3 = bfhi(r.y);
                float a4 = bflo(r.z), a5 = bfhi(r.z), a6 = bflo(r.w), a7 = bfhi(r.w);
                float4 sA = *(const float4*)&scale_s[kb];
                float4 sB = *(const float4*)&scale_s[kb + 4];
                float4 hA = *(const float4*)&shift_s[kb];
                float4 hB = *(const float4*)&shift_s[kb + 4];
                a0 = fmaxf(0.f, fmaf(a0, sA.x, hA.x));
                a1 = fmaxf(0.f, fmaf(a1, sA.y, hA.y));
                a2 = fmaxf(0.f, fmaf(a2, sA.z, hA.z));
                a3 = fmaxf(0.f, fmaf(a3, sA.w, hA.w));
                a4 = fmaxf(0.f, fmaf(a4, sB.x, hB.x));
                a5 = fmaxf(0.f, fmaf(a5, sB.y, hB.y));
                a6 = fmaxf(0.f, fmaf(a6, sB.z, hB.z));
                a7 = fmaxf(0.f, fmaf(a7, sB.w, hB.w));
                Af[k0].u.x = pk2(a0, a1);
                Af[k0].u.y = pk2(a2, a3);
                Af[k0].u.z = pk2(a4, a5);
                Af[k0].u.w = pk2(a6, a7);
            }
        } else {
            const float* xp = (const float*)Xv + ((size_t)row << 7) + (q << 3);
#pragma unroll
            for (int k0 = 0; k0 < 4; ++k0) {
                float4 a = *(const float4*)(xp + (k0 << 5));
                float4 b = *(const float4*)(xp + (k0 << 5) + 4);
                Af[k0].u.x = pk2(a.x, a.y);
                Af[k0].u.y = pk2(a.z, a.w);
                Af[k0].u.z = pk2(b.x, b.y);
                Af[k0].u.w = pk2(b.z, b.w);
            }
        }
    } else {
#pragma unroll
        for (int k0 = 0; k0 < 4; ++k0) Af[k0].u = make_uint4(0, 0, 0, 0);
    }

    f32x4 acc[8];
#pragma unroll
    for (int nt = 0; nt < 8; ++nt) acc[nt] = (f32x4){0.f, 0.f, 0.f, 0.f};

    // unroll 2 (not 8): full unroll kept 32 live uint4 B-frags -> register blowup
#pragma unroll 2
    for (int nt = 0; nt < 8; ++nt) {
        union { uint4 u; bf16x8 v; } Bf[4];
        const size_t bbase = ((size_t)(nt * 16 + c) << 7) + (q << 3);
#pragma unroll
        for (int k0 = 0; k0 < 4; ++k0)
            Bf[k0].u = *(const uint4*)(Wb + bbase + (k0 << 5));
#pragma unroll
        for (int k0 = 0; k0 < 4; ++k0)
            acc[nt] = __builtin_amdgcn_mfma_f32_16x16x32_bf16(Af[k0].v, Bf[k0].v, acc[nt], 0, 0, 0);
    }

    // fused AS/AD; C/D layout col=lane&15, row=q*4+reg
    float ps[4] = {0.f, 0.f, 0.f, 0.f}, pd[4] = {0.f, 0.f, 0.f, 0.f};
#pragma unroll
    for (int nt = 0; nt < 8; ++nt) {
        float av = asrc[nt * 16 + c];
        float dv = adst[nt * 16 + c];
#pragma unroll
        for (int r = 0; r < 4; ++r) {
            ps[r] = fmaf(acc[nt][r], av, ps[r]);
            pd[r] = fmaf(acc[nt][r], dv, pd[r]);
        }
    }
#pragma unroll
    for (int m = 1; m < 16; m <<= 1) {
#pragma unroll
        for (int r = 0; r < 4; ++r) { ps[r] += __shfl_xor(ps[r], m); pd[r] += __shfl_xor(pd[r], m); }
    }
    if (c == 0) {
#pragma unroll
        for (int r = 0; r < 4; ++r) {
            int grow = r0 + q * 4 + r;
            if (grow < NN) { AS[grow] = ps[r]; AD[grow] = pd[r]; }
        }
    }

    // H store via LDS transpose, pk-cvt to bf16
#pragma unroll
    for (int nt = 0; nt < 8; ++nt)
#pragma unroll
        for (int r = 0; r < 4; ++r)
            hst[w][q * 4 + r][nt * 16 + c] = acc[nt][r];
    __syncthreads();
    {
        const int orow = lane >> 2, seg = lane & 3;
        const int grow = r0 + orow;
        if (grow < NN) {
#pragma unroll
            for (int i = 0; i < 4; ++i) {
                float4 a = *(const float4*)&hst[w][orow][seg * 32 + i * 8];
                float4 b = *(const float4*)&hst[w][orow][seg * 32 + i * 8 + 4];
                uint4 o;
                o.x = pk2(a.x, a.y); o.y = pk2(a.z, a.w);
                o.z = pk2(b.x, b.y); o.w = pk2(b.z, b.w);
                *(uint4*)(Hb + ((size_t)grow << 7) + seg * 32 + i * 8) = o;
            }
        }
    }
}

// ======================= per-dst softmax + aggregation (single pass) =======================
// exp without max-subtraction: e = leaky(AS+AD) is O(1); softmax shift-invariant; fp32 exp safe.
// Body = round-0 measured-best (70.3us). OUTBF=1: write bf16 rows (layers 0/1 intermediate).
template<int OUTBF>
__global__ __launch_bounds__(256) void k_agg(
    const int* __restrict__ off, const int* __restrict__ srcs,
    const unsigned short* __restrict__ Hb, const float* __restrict__ AS,
    const float* __restrict__ AD, const float* __restrict__ bias,
    void* __restrict__ OUT)
{
    __shared__ uint2 s_e[4][64];
    const int wid  = threadIdx.x >> 6;
    const int lane = threadIdx.x & 63;
    const int g    = lane >> 4;     // edge subgroup 0..3
    const int x16  = lane & 15;     // 16-lane column group
    const int n    = blockIdx.x * 4 + wid;
    const int beg = off[n], end = off[n + 1];
    const float adn = AD[n];

    float acc[8];
#pragma unroll
    for (int i = 0; i < 8; ++i) acc[i] = 0.f;
    float den = 0.f;

    for (int base = beg; base < end; base += 64) {
        int cnt = end - base; if (cnt > 64) cnt = 64;
        float wgt = 0.f; int s = 0;
        if (lane < cnt) {
            s = srcs[base + lane];
            float e = AS[s] + adn;
            e = (e > 0.f) ? e : 0.2f * e;
            wgt = __expf(e);
        }
        s_e[wid][lane] = make_uint2((unsigned int)s, __builtin_bit_cast(unsigned int, wgt));
        den += wgt;
        int rounds = (cnt + 3) >> 2;
        for (int j = 0; j < rounds; ++j) {
            uint2 ew = s_e[wid][(j << 2) + g];
            float wq = __builtin_bit_cast(float, ew.y);
            uint4 u = *((const uint4*)(Hb + ((size_t)ew.x << 7)) + x16);
            acc[0] = fmaf(wq, bflo(u.x), acc[0]);
            acc[1] = fmaf(wq, bfhi(u.x), acc[1]);
            acc[2] = fmaf(wq, bflo(u.y), acc[2]);
            acc[3] = fmaf(wq, bfhi(u.y), acc[3]);
            acc[4] = fmaf(wq, bflo(u.z), acc[4]);
            acc[5] = fmaf(wq, bfhi(u.z), acc[5]);
            acc[6] = fmaf(wq, bflo(u.w), acc[6]);
            acc[7] = fmaf(wq, bfhi(u.w), acc[7]);
        }
    }

    // reduce partial sums across the 4 edge subgroups; den across all 64 lanes
#pragma unroll
    for (int i = 0; i < 8; ++i) {
        acc[i] += __shfl_xor(acc[i], 16);
        acc[i] += __shfl_xor(acc[i], 32);
    }
#pragma unroll
    for (int o = 32; o; o >>= 1) den += __shfl_xor(den, o);
    float inv = 1.f / den;

    if (g == 0) {
        float4 b1 = *(const float4*)&bias[x16 << 3];
        float4 b2 = *(const float4*)&bias[(x16 << 3) + 4];
        float o0 = fmaf(acc[0], inv, b1.x), o1 = fmaf(acc[1], inv, b1.y);
        float o2 = fmaf(acc[2], inv, b1.z), o3 = fmaf(acc[3], inv, b1.w);
        float o4 = fmaf(acc[4], inv, b2.x), o5 = fmaf(acc[5], inv, b2.y);
        float o6 = fmaf(acc[6], inv, b2.z), o7 = fmaf(acc[7], inv, b2.w);
        if (OUTBF) {
            uint4 pkd;
            pkd.x = pk2(o0, o1); pkd.y = pk2(o2, o3);
            pkd.z = pk2(o4, o5); pkd.w = pk2(o6, o7);
            *(uint4*)((unsigned short*)OUT + ((size_t)n << 7) + (x16 << 3)) = pkd;
        } else {
            float* op = (float*)OUT + ((size_t)n << 7) + (x16 << 3);
            *(float4*)op = make_float4(o0, o1, o2, o3);
            *(float4*)(op + 4) = make_float4(o4, o5, o6, o7);
        }
    }
}

// ======================= batchnorm stats from bf16 rows (vectorized) =======================
__global__ void k_colsum(const unsigned short* __restrict__ Xb,
                         float* __restrict__ gsum, float* __restrict__ gsq) {
    __shared__ float ls[4][16][8], lq[4][16][8];
    const int t = threadIdx.x, cg = t & 15, w = t >> 6, lane = t & 63;
    float s[8], q[8];
#pragma unroll
    for (int i = 0; i < 8; ++i) { s[i] = 0.f; q[i] = 0.f; }
    for (int r = blockIdx.x * 16 + (t >> 4); r < NN; r += STAT_BLOCKS * 16) {
        uint4 v = *(const uint4*)(Xb + ((size_t)r << 7) + (cg << 3));
        float f;
        f = bflo(v.x); s[0] += f; q[0] += f * f;  f = bfhi(v.x); s[1] += f; q[1] += f * f;
        f = bflo(v.y); s[2] += f; q[2] += f * f;  f = bfhi(v.y); s[3] += f; q[3] += f * f;
        f = bflo(v.z); s[4] += f; q[4] += f * f;  f = bfhi(v.z); s[5] += f; q[5] += f * f;
        f = bflo(v.w); s[6] += f; q[6] += f * f;  f = bfhi(v.w); s[7] += f; q[7] += f * f;
    }
    // reduce the 4 row-owners inside the wave (lane bits 4-5)
#pragma unroll
    for (int i = 0; i < 8; ++i) {
        s[i] += __shfl_xor(s[i], 16); s[i] += __shfl_xor(s[i], 32);
        q[i] += __shfl_xor(q[i], 16); q[i] += __shfl_xor(q[i], 32);
    }
    if (lane < 16) {
#pragma unroll
        for (int i = 0; i < 8; ++i) { ls[w][lane][i] = s[i]; lq[w][lane][i] = q[i]; }
    }
    __syncthreads();
    if (t < 16) {
#pragma unroll
        for (int i = 0; i < 8; ++i) {
            float ss = ls[0][t][i] + ls[1][t][i] + ls[2][t][i] + ls[3][t][i];
            float qq = lq[0][t][i] + lq[1][t][i] + lq[2][t][i] + lq[3][t][i];
            atomicAdd(&gsum[t * 8 + i], ss);
            atomicAdd(&gsq[t * 8 + i], qq);
        }
    }
}

extern "C" void kernel_launch(void* const* d_in, const int* in_sizes, int n_in,
                              void* d_out, int out_size, void* d_ws, size_t ws_size,
                              hipStream_t stream)
{
    const float* x  = (const float*)d_in[0];
    const int*   ei = (const int*)d_in[1];
    const float* Wm[3]  = {(const float*)d_in[2], (const float*)d_in[6],  (const float*)d_in[10]};
    const float* Asr[3] = {(const float*)d_in[3], (const float*)d_in[7],  (const float*)d_in[11]};
    const float* Ads[3] = {(const float*)d_in[4], (const float*)d_in[8],  (const float*)d_in[12]};
    const float* Bs[3]  = {(const float*)d_in[5], (const float*)d_in[9],  (const float*)d_in[13]};
    const float* gam[2] = {(const float*)d_in[14], (const float*)d_in[16]};
    const float* bet[2] = {(const float*)d_in[15], (const float*)d_in[17]};

    char* p = (char*)d_ws;
    auto carve = [&](size_t bytes) -> char* {
        char* r = p;
        p += (bytes + 255) & ~(size_t)255;
        return r;
    };
    int*   off_   = (int*)carve((size_t)(NN + 1) * 4);
    int*   srcs   = (int*)carve((size_t)ET * 4);
    unsigned int* bucketed = (unsigned int*)carve((size_t)ET * 4);
    int*   btot   = (int*)carve(256 * 4);
    float* gstat  = (float*)carve(4 * 128 * 4);    // gsum0,gsq0,gsum1,gsq1
    int*   bstart = (int*)carve(260 * 4);
    int*   bcur   = (int*)carve(256 * 4);
    unsigned short* Hb  = (unsigned short*)carve((size_t)NP * 128 * 2);
    unsigned short* Wb  = (unsigned short*)carve((size_t)3 * 16384 * 2);  // contiguous 3 layers
    float* AS    = (float*)carve((size_t)NN * 4);
    float* AD    = (float*)carve((size_t)NN * 4);

    float*          OUTf = (float*)d_out;            // final fp32 output
    unsigned short* OUTb = (unsigned short*)d_out;   // bf16 intermediate aliases lower half;
                                                     // layer-2 mfma reads it fully BEFORE the
                                                     // final fp32 k_agg overwrite (stream order)

    // ---- one cooperative dispatch: zero + cvtw + count + scan + bucket + csr ----
    {
        const int*   a_ei = ei;
        const float* a_w0 = Wm[0]; const float* a_w1 = Wm[1]; const float* a_w2 = Wm[2];
        unsigned short* a_wb = Wb;
        int* a_btot = btot; int* a_bstart = bstart; int* a_bcur = bcur;
        int* a_off = off_;  unsigned int* a_bkt = bucketed; int* a_srcs = srcs;
        float* a_gstat = gstat;
        void* ka[12] = { &a_ei, &a_w0, &a_w1, &a_w2, &a_wb, &a_btot, &a_bstart,
                         &a_bcur, &a_off, &a_bkt, &a_srcs, &a_gstat };
        (void)hipLaunchCooperativeKernel((void*)k_build, dim3(BUILD_GRID), dim3(256),
                                         ka, 0, stream);
    }

    const int MFMA_GRID = NP / 64;

    // layer 0
    k_mfma<0><<<MFMA_GRID, 256, 0, stream>>>(x, Wb, nullptr, nullptr, nullptr, nullptr,
                                             Asr[0], Ads[0], Hb, AS, AD);
    k_agg<1><<<NN / 4, 256, 0, stream>>>(off_, srcs, Hb, AS, AD, Bs[0], OUTb);
    k_colsum<<<STAT_BLOCKS, 256, 0, stream>>>(OUTb, gstat, gstat + 128);

    // layer 1 (BN affine computed inside k_mfma from raw sums; bf16 input)
    k_mfma<1><<<MFMA_GRID, 256, 0, stream>>>(OUTb, Wb + 16384, gstat, gstat + 128,
                                             gam[0], bet[0], Asr[1], Ads[1], Hb, AS, AD);
    k_agg<1><<<NN / 4, 256, 0, stream>>>(off_, srcs, Hb, AS, AD, Bs[1], OUTb);
    k_colsum<<<STAT_BLOCKS, 256, 0, stream>>>(OUTb, gstat + 256, gstat + 384);

    // layer 2 (final fp32 output into d_out)
    k_mfma<1><<<MFMA_GRID, 256, 0, stream>>>(OUTb, Wb + 32768, gstat + 256, gstat + 384,
                                             gam[1], bet[1], Asr[2], Ads[2], Hb, AS, AD);
    k_agg<0><<<NN / 4, 256, 0, stream>>>(off_, srcs, Hb, AS, AD, Bs[2], OUTf);
}

// Round 5
// 679.099 us; speedup vs baseline: 1.4685x; 1.4685x over previous
//
#include <hip/hip_runtime.h>
#include <cstdint>
#include <cstddef>

#define NN 100000
#define NP 100096          // rows padded to multiple of 64
#define EE 1600000
#define ET 1700000         // EE + NN self-loops
#define NBKT 196           // ceil(NN/512) dst-range buckets
#define TILE 2048          // edges per k_bucket block
#define STAT_BLOCKS 400

typedef short  bf16x8 __attribute__((ext_vector_type(8)));
typedef float  f32x4  __attribute__((ext_vector_type(4)));

__device__ __forceinline__ unsigned short f2bf(float f) {
    unsigned int x = __builtin_bit_cast(unsigned int, f);
    x += 0x7FFFu + ((x >> 16) & 1u);   // RNE
    return (unsigned short)(x >> 16);
}
__device__ __forceinline__ unsigned int pk2(float lo, float hi) {
    return ((unsigned int)f2bf(hi) << 16) | (unsigned int)f2bf(lo);
}
__device__ __forceinline__ float bflo(unsigned int u) {
    return __builtin_bit_cast(float, u << 16);
}
__device__ __forceinline__ float bfhi(unsigned int u) {
    return __builtin_bit_cast(float, u & 0xFFFF0000u);
}

// ======================= CSR build via 2-level bucket sort =======================
// bucket = dst >> 9 (512 dsts per bucket); packed edge = (dst&511)<<17 | src
// NOTE (r4 post-mortem): cooperative-kernel fusion of these phases regressed 6x —
// grid.sync() with 831 blocks spins ~90us/sync (VALUBusy 0.8%). Keep separate dispatches.

__global__ void k_bcount(const int* __restrict__ ei, int* __restrict__ btot) {
    __shared__ int h[256];
    int t = threadIdx.x;
    h[t] = 0;
    __syncthreads();
    for (int e = blockIdx.x * 256 + t; e < ET; e += 256 * 256) {
        int d = (e < EE) ? ei[EE + e] : (e - EE);
        atomicAdd(&h[d >> 9], 1);
    }
    __syncthreads();
    if (h[t]) atomicAdd(&btot[t], h[t]);
}

__global__ void k_bscan(const int* __restrict__ btot, int* __restrict__ bstart,
                        int* __restrict__ bcur, int* __restrict__ off) {
    __shared__ int s[256];
    int t = threadIdx.x;
    int v = (t < NBKT) ? btot[t] : 0;
    s[t] = v;
    __syncthreads();
    for (int o = 1; o < 256; o <<= 1) {
        int a = (t >= o) ? s[t - o] : 0;
        __syncthreads();
        s[t] += a;
        __syncthreads();
    }
    int ex = s[t] - v;
    if (t <= NBKT) bstart[t] = (t < NBKT) ? ex : ET;
    if (t == NBKT - 1) bstart[NBKT] = s[t];   // == ET
    bcur[t] = ex;
    if (t == 0) off[NN] = ET;
}

__global__ __launch_bounds__(256) void k_bucket(
    const int* __restrict__ ei, int* __restrict__ bcur, unsigned int* __restrict__ bucketed)
{
    __shared__ int h4[4][256], woff[4][256], loff[256], gbase[256], sc[256];
    __shared__ unsigned int stage[TILE];
    __shared__ int gaddr[TILE];
    __shared__ int stot_s;
    const int t = threadIdx.x;
    const int w = t >> 6;
    const int e0 = blockIdx.x * TILE;

    h4[0][t] = 0; h4[1][t] = 0; h4[2][t] = 0; h4[3][t] = 0;
    __syncthreads();

    unsigned int pk[TILE / 256];
    int bk[TILE / 256];
#pragma unroll
    for (int i = 0; i < TILE / 256; ++i) {
        int e = e0 + i * 256 + t;
        bk[i] = -1;
        if (e < ET) {
            int s, d;
            if (e < EE) { s = ei[e]; d = ei[EE + e]; } else { s = e - EE; d = s; }
            bk[i] = d >> 9;
            pk[i] = ((unsigned int)(d & 511) << 17) | (unsigned int)s;
            atomicAdd(&h4[w][bk[i]], 1);
        }
    }
    __syncthreads();

    // per-bucket totals + inclusive scan
    int h0 = h4[0][t], h1 = h4[1][t], h2 = h4[2][t], h3 = h4[3][t];
    int tot = h0 + h1 + h2 + h3;
    sc[t] = tot;
    __syncthreads();
    for (int o = 1; o < 256; o <<= 1) {
        int a = (t >= o) ? sc[t - o] : 0;
        __syncthreads();
        sc[t] += a;
        __syncthreads();
    }
    int lo = sc[t] - tot;
    loff[t] = lo;
    woff[0][t] = lo;
    woff[1][t] = lo + h0;
    woff[2][t] = lo + h0 + h1;
    woff[3][t] = lo + h0 + h1 + h2;
    if (t < NBKT && tot) gbase[t] = atomicAdd(&bcur[t], tot);
    if (t == 255) stot_s = sc[255];
    h4[0][t] = 0; h4[1][t] = 0; h4[2][t] = 0; h4[3][t] = 0;
    __syncthreads();

    // rank (per-wave counters -> 4x less LDS-atomic contention) + stage
#pragma unroll
    for (int i = 0; i < TILE / 256; ++i) {
        if (bk[i] >= 0) {
            int b = bk[i];
            int r = woff[w][b] + atomicAdd(&h4[w][b], 1);
            stage[r] = pk[i];
            gaddr[r] = gbase[b] + (r - loff[b]);
        }
    }
    __syncthreads();

    const int stot = stot_s;
    for (int j = t; j < stot; j += 256)
        bucketed[gaddr[j]] = stage[j];
}

__global__ __launch_bounds__(256) void k_csr(
    const unsigned int* __restrict__ bucketed, const int* __restrict__ bstart,
    int* __restrict__ off, int* __restrict__ srcs)
{
    __shared__ int h[512], sc2[512], c2[512], sp[256];
    const int t = threadIdx.x;
    const int b = blockIdx.x;
    const int beg = bstart[b], end = bstart[b + 1];
    const int cnt = end - beg;

    h[t] = 0; h[t + 256] = 0; c2[t] = 0; c2[t + 256] = 0;
    __syncthreads();
    for (int i = t; i < cnt; i += 256)
        atomicAdd(&h[bucketed[beg + i] >> 17], 1);
    __syncthreads();

    int a0 = h[2 * t], a1 = h[2 * t + 1];
    sp[t] = a0 + a1;
    __syncthreads();
    for (int o = 1; o < 256; o <<= 1) {
        int a = (t >= o) ? sp[t - o] : 0;
        __syncthreads();
        sp[t] += a;
        __syncthreads();
    }
    int ep = sp[t] - (a0 + a1);
    sc2[2 * t] = ep;
    sc2[2 * t + 1] = ep + a0;
    __syncthreads();

    const int d0 = b << 9;
#pragma unroll
    for (int k = t; k < 512; k += 256) {
        int d = d0 + k;
        if (d < NN) off[d] = beg + sc2[k];
    }

    for (int i = t; i < cnt; i += 256) {
        unsigned int v = bucketed[beg + i];
        int ld = v >> 17;
        int r = atomicAdd(&c2[ld], 1);
        srcs[beg + sc2[ld] + r] = (int)(v & 0x1FFFFu);
    }
}

// ======================= weight conversion (all 3 layers, one launch) =======================
__global__ void k_cvtw3(const float* __restrict__ W0, const float* __restrict__ W1,
                        const float* __restrict__ W2, unsigned short* __restrict__ Wb) {
    int i = blockIdx.x * 256 + threadIdx.x;   // 49152 elements
    const float* W = (i < 16384) ? W0 : (i < 32768) ? W1 : W2;
    Wb[i] = f2bf(W[i & 16383]);
}

// ======================= MFMA GEMM: H = X @ W^T, fused BN-affine/relu/cvt + AS/AD ===========
// MODE 0: fp32 X read (layer 0); MODE 1: bf16 X read + BN affine (from raw stats) + relu
template<int MODE>
__global__ __launch_bounds__(256) void k_mfma(
    const void* __restrict__ Xv, const unsigned short* __restrict__ Wb,
    const float* __restrict__ gsum, const float* __restrict__ gsq,
    const float* __restrict__ gamma, const float* __restrict__ beta,
    const float* __restrict__ asrc, const float* __restrict__ adst,
    unsigned short* __restrict__ Hb, float* __restrict__ AS, float* __restrict__ AD)
{
    __shared__ float hst[4][16][132];
    __shared__ float scale_s[128], shift_s[128];
    const int t    = threadIdx.x;
    const int w    = t >> 6;
    const int lane = t & 63;
    const int c    = lane & 15;
    const int q    = lane >> 4;
    const int r0   = blockIdx.x * 64 + w * 16;
    const int row  = r0 + c;

    if (MODE) {
        // BN final stage fused here: per-column affine from raw sums (once per block)
        if (t < 128) {
            float mu  = gsum[t] * (1.f / NN);
            float var = gsq[t] * (1.f / NN) - mu * mu;
            float sc  = gamma[t] * rsqrtf(var + 1e-5f);
            scale_s[t] = sc;
            shift_s[t] = beta[t] - mu * sc;
        }
        __syncthreads();
    }

    union { uint4 u; bf16x8 v; } Af[4];
    if (row < NN) {
        if (MODE) {
            const unsigned short* xp = (const unsigned short*)Xv + ((size_t)row << 7) + (q << 3);
#pragma unroll
            for (int k0 = 0; k0 < 4; ++k0) {
                uint4 r = *(const uint4*)(xp + (k0 << 5));
                const int kb = (k0 << 5) + (q << 3);
                float a0 = bflo(r.x), a1 = bfhi(r.x), a2 = bflo(r.y), a3 = bfhi(r.y);
                float a4 = bflo(r.z), a5 = bfhi(r.z), a6 = bflo(r.w), a7 = bfhi(r.w);
                float4 sA = *(const float4*)&scale_s[kb];
                float4 sB = *(const float4*)&scale_s[kb + 4];
                float4 hA = *(const float4*)&shift_s[kb];
                float4 hB = *(const float4*)&shift_s[kb + 4];
                a0 = fmaxf(0.f, fmaf(a0, sA.x, hA.x));
                a1 = fmaxf(0.f, fmaf(a1, sA.y, hA.y));
                a2 = fmaxf(0.f, fmaf(a2, sA.z, hA.z));
                a3 = fmaxf(0.f, fmaf(a3, sA.w, hA.w));
                a4 = fmaxf(0.f, fmaf(a4, sB.x, hB.x));
                a5 = fmaxf(0.f, fmaf(a5, sB.y, hB.y));
                a6 = fmaxf(0.f, fmaf(a6, sB.z, hB.z));
                a7 = fmaxf(0.f, fmaf(a7, sB.w, hB.w));
                Af[k0].u.x = pk2(a0, a1);
                Af[k0].u.y = pk2(a2, a3);
                Af[k0].u.z = pk2(a4, a5);
                Af[k0].u.w = pk2(a6, a7);
            }
        } else {
            const float* xp = (const float*)Xv + ((size_t)row << 7) + (q << 3);
#pragma unroll
            for (int k0 = 0; k0 < 4; ++k0) {
                float4 a = *(const float4*)(xp + (k0 << 5));
                float4 b = *(const float4*)(xp + (k0 << 5) + 4);
                Af[k0].u.x = pk2(a.x, a.y);
                Af[k0].u.y = pk2(a.z, a.w);
                Af[k0].u.z = pk2(b.x, b.y);
                Af[k0].u.w = pk2(b.z, b.w);
            }
        }
    } else {
#pragma unroll
        for (int k0 = 0; k0 < 4; ++k0) Af[k0].u = make_uint4(0, 0, 0, 0);
    }

    f32x4 acc[8];
#pragma unroll
    for (int nt = 0; nt < 8; ++nt) acc[nt] = (f32x4){0.f, 0.f, 0.f, 0.f};

#pragma unroll
    for (int nt = 0; nt < 8; ++nt) {
        union { uint4 u; bf16x8 v; } Bf[4];
        const size_t bbase = ((size_t)(nt * 16 + c) << 7) + (q << 3);
#pragma unroll
        for (int k0 = 0; k0 < 4; ++k0)
            Bf[k0].u = *(const uint4*)(Wb + bbase + (k0 << 5));
#pragma unroll
        for (int k0 = 0; k0 < 4; ++k0)
            acc[nt] = __builtin_amdgcn_mfma_f32_16x16x32_bf16(Af[k0].v, Bf[k0].v, acc[nt], 0, 0, 0);
    }

    // fused AS/AD; C/D layout col=lane&15, row=q*4+reg
    float ps[4] = {0.f, 0.f, 0.f, 0.f}, pd[4] = {0.f, 0.f, 0.f, 0.f};
#pragma unroll
    for (int nt = 0; nt < 8; ++nt) {
        float av = asrc[nt * 16 + c];
        float dv = adst[nt * 16 + c];
#pragma unroll
        for (int r = 0; r < 4; ++r) {
            ps[r] = fmaf(acc[nt][r], av, ps[r]);
            pd[r] = fmaf(acc[nt][r], dv, pd[r]);
        }
    }
#pragma unroll
    for (int m = 1; m < 16; m <<= 1) {
#pragma unroll
        for (int r = 0; r < 4; ++r) { ps[r] += __shfl_xor(ps[r], m); pd[r] += __shfl_xor(pd[r], m); }
    }
    if (c == 0) {
#pragma unroll
        for (int r = 0; r < 4; ++r) {
            int grow = r0 + q * 4 + r;
            if (grow < NN) { AS[grow] = ps[r]; AD[grow] = pd[r]; }
        }
    }

    // H store via LDS transpose, pk-cvt to bf16
#pragma unroll
    for (int nt = 0; nt < 8; ++nt)
#pragma unroll
        for (int r = 0; r < 4; ++r)
            hst[w][q * 4 + r][nt * 16 + c] = acc[nt][r];
    __syncthreads();
    {
        const int orow = lane >> 2, seg = lane & 3;
        const int grow = r0 + orow;
        if (grow < NN) {
#pragma unroll
            for (int i = 0; i < 4; ++i) {
                float4 a = *(const float4*)&hst[w][orow][seg * 32 + i * 8];
                float4 b = *(const float4*)&hst[w][orow][seg * 32 + i * 8 + 4];
                uint4 o;
                o.x = pk2(a.x, a.y); o.y = pk2(a.z, a.w);
                o.z = pk2(b.x, b.y); o.w = pk2(b.z, b.w);
                *(uint4*)(Hb + ((size_t)grow << 7) + seg * 32 + i * 8) = o;
            }
        }
    }
}

// ======================= per-dst softmax + aggregation (single pass) =======================
// exp without max-subtraction: e = leaky(AS+AD) is O(1); softmax shift-invariant; fp32 exp safe.
// Body = round-0 measured-best. OUTBF=1: write bf16 rows (layers 0/1 intermediate) — halves
// the write traffic; verified correctness-neutral in r4 (absmax unchanged).
template<int OUTBF>
__global__ __launch_bounds__(256) void k_agg(
    const int* __restrict__ off, const int* __restrict__ srcs,
    const unsigned short* __restrict__ Hb, const float* __restrict__ AS,
    const float* __restrict__ AD, const float* __restrict__ bias,
    void* __restrict__ OUT)
{
    __shared__ uint2 s_e[4][64];
    const int wid  = threadIdx.x >> 6;
    const int lane = threadIdx.x & 63;
    const int g    = lane >> 4;     // edge subgroup 0..3
    const int x16  = lane & 15;     // 16-lane column group
    const int n    = blockIdx.x * 4 + wid;
    const int beg = off[n], end = off[n + 1];
    const float adn = AD[n];

    float acc[8];
#pragma unroll
    for (int i = 0; i < 8; ++i) acc[i] = 0.f;
    float den = 0.f;

    for (int base = beg; base < end; base += 64) {
        int cnt = end - base; if (cnt > 64) cnt = 64;
        float wgt = 0.f; int s = 0;
        if (lane < cnt) {
            s = srcs[base + lane];
            float e = AS[s] + adn;
            e = (e > 0.f) ? e : 0.2f * e;
            wgt = __expf(e);
        }
        s_e[wid][lane] = make_uint2((unsigned int)s, __builtin_bit_cast(unsigned int, wgt));
        den += wgt;
        int rounds = (cnt + 3) >> 2;
        for (int j = 0; j < rounds; ++j) {
            uint2 ew = s_e[wid][(j << 2) + g];
            float wq = __builtin_bit_cast(float, ew.y);
            uint4 u = *((const uint4*)(Hb + ((size_t)ew.x << 7)) + x16);
            acc[0] = fmaf(wq, bflo(u.x), acc[0]);
            acc[1] = fmaf(wq, bfhi(u.x), acc[1]);
            acc[2] = fmaf(wq, bflo(u.y), acc[2]);
            acc[3] = fmaf(wq, bfhi(u.y), acc[3]);
            acc[4] = fmaf(wq, bflo(u.z), acc[4]);
            acc[5] = fmaf(wq, bfhi(u.z), acc[5]);
            acc[6] = fmaf(wq, bflo(u.w), acc[6]);
            acc[7] = fmaf(wq, bfhi(u.w), acc[7]);
        }
    }

    // reduce partial sums across the 4 edge subgroups; den across all 64 lanes
#pragma unroll
    for (int i = 0; i < 8; ++i) {
        acc[i] += __shfl_xor(acc[i], 16);
        acc[i] += __shfl_xor(acc[i], 32);
    }
#pragma unroll
    for (int o = 32; o; o >>= 1) den += __shfl_xor(den, o);
    float inv = 1.f / den;

    if (g == 0) {
        float4 b1 = *(const float4*)&bias[x16 << 3];
        float4 b2 = *(const float4*)&bias[(x16 << 3) + 4];
        float o0 = fmaf(acc[0], inv, b1.x), o1 = fmaf(acc[1], inv, b1.y);
        float o2 = fmaf(acc[2], inv, b1.z), o3 = fmaf(acc[3], inv, b1.w);
        float o4 = fmaf(acc[4], inv, b2.x), o5 = fmaf(acc[5], inv, b2.y);
        float o6 = fmaf(acc[6], inv, b2.z), o7 = fmaf(acc[7], inv, b2.w);
        if (OUTBF) {
            uint4 pkd;
            pkd.x = pk2(o0, o1); pkd.y = pk2(o2, o3);
            pkd.z = pk2(o4, o5); pkd.w = pk2(o6, o7);
            *(uint4*)((unsigned short*)OUT + ((size_t)n << 7) + (x16 << 3)) = pkd;
        } else {
            float* op = (float*)OUT + ((size_t)n << 7) + (x16 << 3);
            *(float4*)op = make_float4(o0, o1, o2, o3);
            *(float4*)(op + 4) = make_float4(o4, o5, o6, o7);
        }
    }
}

// ======================= batchnorm stats from bf16 rows (vectorized) =======================
__global__ void k_colsum(const unsigned short* __restrict__ Xb,
                         float* __restrict__ gsum, float* __restrict__ gsq) {
    __shared__ float ls[4][16][8], lq[4][16][8];
    const int t = threadIdx.x, cg = t & 15, w = t >> 6, lane = t & 63;
    float s[8], q[8];
#pragma unroll
    for (int i = 0; i < 8; ++i) { s[i] = 0.f; q[i] = 0.f; }
    for (int r = blockIdx.x * 16 + (t >> 4); r < NN; r += STAT_BLOCKS * 16) {
        uint4 v = *(const uint4*)(Xb + ((size_t)r << 7) + (cg << 3));
        float f;
        f = bflo(v.x); s[0] += f; q[0] += f * f;  f = bfhi(v.x); s[1] += f; q[1] += f * f;
        f = bflo(v.y); s[2] += f; q[2] += f * f;  f = bfhi(v.y); s[3] += f; q[3] += f * f;
        f = bflo(v.z); s[4] += f; q[4] += f * f;  f = bfhi(v.z); s[5] += f; q[5] += f * f;
        f = bflo(v.w); s[6] += f; q[6] += f * f;  f = bfhi(v.w); s[7] += f; q[7] += f * f;
    }
    // reduce the 4 row-owners inside the wave (lane bits 4-5 carry row low bits)
#pragma unroll
    for (int i = 0; i < 8; ++i) {
        s[i] += __shfl_xor(s[i], 16); s[i] += __shfl_xor(s[i], 32);
        q[i] += __shfl_xor(q[i], 16); q[i] += __shfl_xor(q[i], 32);
    }
    if (lane < 16) {
#pragma unroll
        for (int i = 0; i < 8; ++i) { ls[w][lane][i] = s[i]; lq[w][lane][i] = q[i]; }
    }
    __syncthreads();
    if (t < 16) {
#pragma unroll
        for (int i = 0; i < 8; ++i) {
            float ss = ls[0][t][i] + ls[1][t][i] + ls[2][t][i] + ls[3][t][i];
            float qq = lq[0][t][i] + lq[1][t][i] + lq[2][t][i] + lq[3][t][i];
            atomicAdd(&gsum[t * 8 + i], ss);
            atomicAdd(&gsq[t * 8 + i], qq);
        }
    }
}

extern "C" void kernel_launch(void* const* d_in, const int* in_sizes, int n_in,
                              void* d_out, int out_size, void* d_ws, size_t ws_size,
                              hipStream_t stream)
{
    const float* x  = (const float*)d_in[0];
    const int*   ei = (const int*)d_in[1];
    const float* Wm[3]  = {(const float*)d_in[2], (const float*)d_in[6],  (const float*)d_in[10]};
    const float* Asr[3] = {(const float*)d_in[3], (const float*)d_in[7],  (const float*)d_in[11]};
    const float* Ads[3] = {(const float*)d_in[4], (const float*)d_in[8],  (const float*)d_in[12]};
    const float* Bs[3]  = {(const float*)d_in[5], (const float*)d_in[9],  (const float*)d_in[13]};
    const float* gam[2] = {(const float*)d_in[14], (const float*)d_in[16]};
    const float* bet[2] = {(const float*)d_in[15], (const float*)d_in[17]};

    char* p = (char*)d_ws;
    auto carve = [&](size_t bytes) -> char* {
        char* r = p;
        p += (bytes + 255) & ~(size_t)255;
        return r;
    };
    int*   off_   = (int*)carve((size_t)(NN + 1) * 4);
    int*   srcs   = (int*)carve((size_t)ET * 4);
    unsigned int* bucketed = (unsigned int*)carve((size_t)ET * 4);
    int*   btot   = (int*)carve(256 * 4);          // 1024 B, followed immediately by...
    float* gstat  = (float*)carve(4 * 128 * 4);    // gsum0,gsq0,gsum1,gsq1 (2048 B) — one memset
    int*   bstart = (int*)carve(260 * 4);
    int*   bcur   = (int*)carve(256 * 4);
    unsigned short* Hb  = (unsigned short*)carve((size_t)NP * 128 * 2);
    unsigned short* Wb  = (unsigned short*)carve((size_t)3 * 16384 * 2);  // contiguous 3 layers
    float* AS    = (float*)carve((size_t)NN * 4);
    float* AD    = (float*)carve((size_t)NN * 4);

    float*          OUTf = (float*)d_out;            // final fp32 output
    unsigned short* OUTb = (unsigned short*)d_out;   // bf16 intermediate aliases lower half;
                                                     // layer-N mfma reads it fully BEFORE the
                                                     // next k_agg overwrite (stream order)

    // zero btot + all 4 stat vectors in one shot (they are carved adjacently)
    (void)hipMemsetAsync(btot, 0, 256 * 4 + 4 * 128 * 4, stream);

    // CSR build (bucket sort)
    k_bcount<<<256, 256, 0, stream>>>(ei, btot);
    k_bscan<<<1, 256, 0, stream>>>(btot, bstart, bcur, off_);
    k_bucket<<<(ET + TILE - 1) / TILE, 256, 0, stream>>>(ei, bcur, bucketed);
    k_csr<<<NBKT, 256, 0, stream>>>(bucketed, bstart, off_, srcs);

    // weight conversions (single launch)
    k_cvtw3<<<192, 256, 0, stream>>>(Wm[0], Wm[1], Wm[2], Wb);

    const int MFMA_GRID = NP / 64;

    // layer 0
    k_mfma<0><<<MFMA_GRID, 256, 0, stream>>>(x, Wb, nullptr, nullptr, nullptr, nullptr,
                                             Asr[0], Ads[0], Hb, AS, AD);
    k_agg<1><<<NN / 4, 256, 0, stream>>>(off_, srcs, Hb, AS, AD, Bs[0], OUTb);
    k_colsum<<<STAT_BLOCKS, 256, 0, stream>>>(OUTb, gstat, gstat + 128);

    // layer 1 (BN affine computed inside k_mfma from raw sums; bf16 input)
    k_mfma<1><<<MFMA_GRID, 256, 0, stream>>>(OUTb, Wb + 16384, gstat, gstat + 128,
                                             gam[0], bet[0], Asr[1], Ads[1], Hb, AS, AD);
    k_agg<1><<<NN / 4, 256, 0, stream>>>(off_, srcs, Hb, AS, AD, Bs[1], OUTb);
    k_colsum<<<STAT_BLOCKS, 256, 0, stream>>>(OUTb, gstat + 256, gstat + 384);

    // layer 2 (final fp32 output into d_out)
    k_mfma<1><<<MFMA_GRID, 256, 0, stream>>>(OUTb, Wb + 32768, gstat + 256, gstat + 384,
                                             gam[1], bet[1], Asr[2], Ads[2], Hb, AS, AD);
    k_agg<0><<<NN / 4, 256, 0, stream>>>(off_, srcs, Hb, AS, AD, Bs[2], OUTf);
}

// Round 6
// 562.400 us; speedup vs baseline: 1.7732x; 1.2075x over previous
//
#include <hip/hip_runtime.h>
#include <cstdint>
#include <cstddef>

#define NN 100000
#define NP 100096          // rows padded to multiple of 64
#define EE 1600000
#define ET 1700000         // EE + NN self-loops
#define NBKT 196           // ceil(NN/512) dst-range buckets
#define TILE 2048          // edges per k_bucket block
#define STAT_BLOCKS 400

typedef short  bf16x8 __attribute__((ext_vector_type(8)));
typedef float  f32x4  __attribute__((ext_vector_type(4)));

__device__ __forceinline__ unsigned short f2bf(float f) {
    unsigned int x = __builtin_bit_cast(unsigned int, f);
    x += 0x7FFFu + ((x >> 16) & 1u);   // RNE
    return (unsigned short)(x >> 16);
}
__device__ __forceinline__ unsigned int pk2(float lo, float hi) {
    return ((unsigned int)f2bf(hi) << 16) | (unsigned int)f2bf(lo);
}
__device__ __forceinline__ float bflo(unsigned int u) {
    return __builtin_bit_cast(float, u << 16);
}
__device__ __forceinline__ float bfhi(unsigned int u) {
    return __builtin_bit_cast(float, u & 0xFFFF0000u);
}

// ======================= CSR build via 2-level bucket sort =======================
// bucket = dst >> 9 (512 dsts per bucket); packed edge = (dst&511)<<17 | src
// NOTE (r4 post-mortem): cooperative-kernel fusion of these phases regressed 6x —
// grid.sync() with 831 blocks spins ~90us/sync (VALUBusy 0.8%). Keep separate dispatches.

__global__ void k_bcount(const int* __restrict__ ei, int* __restrict__ btot) {
    __shared__ int h[256];
    int t = threadIdx.x;
    h[t] = 0;
    __syncthreads();
    for (int e = blockIdx.x * 256 + t; e < ET; e += 256 * 256) {
        int d = (e < EE) ? ei[EE + e] : (e - EE);
        atomicAdd(&h[d >> 9], 1);
    }
    __syncthreads();
    if (h[t]) atomicAdd(&btot[t], h[t]);
}

__global__ void k_bscan(const int* __restrict__ btot, int* __restrict__ bstart,
                        int* __restrict__ bcur, int* __restrict__ off) {
    __shared__ int s[256];
    int t = threadIdx.x;
    int v = (t < NBKT) ? btot[t] : 0;
    s[t] = v;
    __syncthreads();
    for (int o = 1; o < 256; o <<= 1) {
        int a = (t >= o) ? s[t - o] : 0;
        __syncthreads();
        s[t] += a;
        __syncthreads();
    }
    int ex = s[t] - v;
    if (t <= NBKT) bstart[t] = (t < NBKT) ? ex : ET;
    if (t == NBKT - 1) bstart[NBKT] = s[t];   // == ET
    bcur[t] = ex;
    if (t == 0) off[NN] = ET;
}

__global__ __launch_bounds__(256) void k_bucket(
    const int* __restrict__ ei, int* __restrict__ bcur, unsigned int* __restrict__ bucketed)
{
    __shared__ int h4[4][256], woff[4][256], loff[256], gbase[256], sc[256];
    __shared__ unsigned int stage[TILE];
    __shared__ int gaddr[TILE];
    __shared__ int stot_s;
    const int t = threadIdx.x;
    const int w = t >> 6;
    const int e0 = blockIdx.x * TILE;

    h4[0][t] = 0; h4[1][t] = 0; h4[2][t] = 0; h4[3][t] = 0;
    __syncthreads();

    unsigned int pk[TILE / 256];
    int bk[TILE / 256];
#pragma unroll
    for (int i = 0; i < TILE / 256; ++i) {
        int e = e0 + i * 256 + t;
        bk[i] = -1;
        if (e < ET) {
            int s, d;
            if (e < EE) { s = ei[e]; d = ei[EE + e]; } else { s = e - EE; d = s; }
            bk[i] = d >> 9;
            pk[i] = ((unsigned int)(d & 511) << 17) | (unsigned int)s;
            atomicAdd(&h4[w][bk[i]], 1);
        }
    }
    __syncthreads();

    // per-bucket totals + inclusive scan
    int h0 = h4[0][t], h1 = h4[1][t], h2 = h4[2][t], h3 = h4[3][t];
    int tot = h0 + h1 + h2 + h3;
    sc[t] = tot;
    __syncthreads();
    for (int o = 1; o < 256; o <<= 1) {
        int a = (t >= o) ? sc[t - o] : 0;
        __syncthreads();
        sc[t] += a;
        __syncthreads();
    }
    int lo = sc[t] - tot;
    loff[t] = lo;
    woff[0][t] = lo;
    woff[1][t] = lo + h0;
    woff[2][t] = lo + h0 + h1;
    woff[3][t] = lo + h0 + h1 + h2;
    if (t < NBKT && tot) gbase[t] = atomicAdd(&bcur[t], tot);
    if (t == 255) stot_s = sc[255];
    h4[0][t] = 0; h4[1][t] = 0; h4[2][t] = 0; h4[3][t] = 0;
    __syncthreads();

    // rank (per-wave counters -> 4x less LDS-atomic contention) + stage
#pragma unroll
    for (int i = 0; i < TILE / 256; ++i) {
        if (bk[i] >= 0) {
            int b = bk[i];
            int r = woff[w][b] + atomicAdd(&h4[w][b], 1);
            stage[r] = pk[i];
            gaddr[r] = gbase[b] + (r - loff[b]);
        }
    }
    __syncthreads();

    const int stot = stot_s;
    for (int j = t; j < stot; j += 256)
        bucketed[gaddr[j]] = stage[j];
}

__global__ __launch_bounds__(256) void k_csr(
    const unsigned int* __restrict__ bucketed, const int* __restrict__ bstart,
    int* __restrict__ off, int* __restrict__ srcs)
{
    __shared__ int h[512], sc2[512], c2[512], sp[256];
    const int t = threadIdx.x;
    const int b = blockIdx.x;
    const int beg = bstart[b], end = bstart[b + 1];
    const int cnt = end - beg;

    h[t] = 0; h[t + 256] = 0; c2[t] = 0; c2[t + 256] = 0;
    __syncthreads();
    for (int i = t; i < cnt; i += 256)
        atomicAdd(&h[bucketed[beg + i] >> 17], 1);
    __syncthreads();

    int a0 = h[2 * t], a1 = h[2 * t + 1];
    sp[t] = a0 + a1;
    __syncthreads();
    for (int o = 1; o < 256; o <<= 1) {
        int a = (t >= o) ? sp[t - o] : 0;
        __syncthreads();
        sp[t] += a;
        __syncthreads();
    }
    int ep = sp[t] - (a0 + a1);
    sc2[2 * t] = ep;
    sc2[2 * t + 1] = ep + a0;
    __syncthreads();

    const int d0 = b << 9;
#pragma unroll
    for (int k = t; k < 512; k += 256) {
        int d = d0 + k;
        if (d < NN) off[d] = beg + sc2[k];
    }

    for (int i = t; i < cnt; i += 256) {
        unsigned int v = bucketed[beg + i];
        int ld = v >> 17;
        int r = atomicAdd(&c2[ld], 1);
        srcs[beg + sc2[ld] + r] = (int)(v & 0x1FFFFu);
    }
}

// ======================= weight conversion (all 3 layers, one launch) =======================
__global__ void k_cvtw3(const float* __restrict__ W0, const float* __restrict__ W1,
                        const float* __restrict__ W2, unsigned short* __restrict__ Wb) {
    int i = blockIdx.x * 256 + threadIdx.x;   // 49152 elements
    const float* W = (i < 16384) ? W0 : (i < 32768) ? W1 : W2;
    Wb[i] = f2bf(W[i & 16383]);
}

// ======================= MFMA GEMM: H = X @ W^T, fused BN-affine/relu/cvt + AS/AD ===========
// MODE 0: fp32 X read (layer 0); MODE 1: bf16 X read + BN affine (from raw stats) + relu
template<int MODE>
__global__ __launch_bounds__(256) void k_mfma(
    const void* __restrict__ Xv, const unsigned short* __restrict__ Wb,
    const float* __restrict__ gsum, const float* __restrict__ gsq,
    const float* __restrict__ gamma, const float* __restrict__ beta,
    const float* __restrict__ asrc, const float* __restrict__ adst,
    unsigned short* __restrict__ Hb, float* __restrict__ AS, float* __restrict__ AD)
{
    __shared__ float hst[4][16][132];
    __shared__ float scale_s[128], shift_s[128];
    const int t    = threadIdx.x;
    const int w    = t >> 6;
    const int lane = t & 63;
    const int c    = lane & 15;
    const int q    = lane >> 4;
    const int r0   = blockIdx.x * 64 + w * 16;
    const int row  = r0 + c;

    if (MODE) {
        // BN final stage fused here: per-column affine from raw sums (once per block)
        if (t < 128) {
            float mu  = gsum[t] * (1.f / NN);
            float var = gsq[t] * (1.f / NN) - mu * mu;
            float sc  = gamma[t] * rsqrtf(var + 1e-5f);
            scale_s[t] = sc;
            shift_s[t] = beta[t] - mu * sc;
        }
        __syncthreads();
    }

    union { uint4 u; bf16x8 v; } Af[4];
    if (row < NN) {
        if (MODE) {
            const unsigned short* xp = (const unsigned short*)Xv + ((size_t)row << 7) + (q << 3);
#pragma unroll
            for (int k0 = 0; k0 < 4; ++k0) {
                uint4 r = *(const uint4*)(xp + (k0 << 5));
                const int kb = (k0 << 5) + (q << 3);
                float a0 = bflo(r.x), a1 = bfhi(r.x), a2 = bflo(r.y), a3 = bfhi(r.y);
                float a4 = bflo(r.z), a5 = bfhi(r.z), a6 = bflo(r.w), a7 = bfhi(r.w);
                float4 sA = *(const float4*)&scale_s[kb];
                float4 sB = *(const float4*)&scale_s[kb + 4];
                float4 hA = *(const float4*)&shift_s[kb];
                float4 hB = *(const float4*)&shift_s[kb + 4];
                a0 = fmaxf(0.f, fmaf(a0, sA.x, hA.x));
                a1 = fmaxf(0.f, fmaf(a1, sA.y, hA.y));
                a2 = fmaxf(0.f, fmaf(a2, sA.z, hA.z));
                a3 = fmaxf(0.f, fmaf(a3, sA.w, hA.w));
                a4 = fmaxf(0.f, fmaf(a4, sB.x, hB.x));
                a5 = fmaxf(0.f, fmaf(a5, sB.y, hB.y));
                a6 = fmaxf(0.f, fmaf(a6, sB.z, hB.z));
                a7 = fmaxf(0.f, fmaf(a7, sB.w, hB.w));
                Af[k0].u.x = pk2(a0, a1);
                Af[k0].u.y = pk2(a2, a3);
                Af[k0].u.z = pk2(a4, a5);
                Af[k0].u.w = pk2(a6, a7);
            }
        } else {
            const float* xp = (const float*)Xv + ((size_t)row << 7) + (q << 3);
#pragma unroll
            for (int k0 = 0; k0 < 4; ++k0) {
                float4 a = *(const float4*)(xp + (k0 << 5));
                float4 b = *(const float4*)(xp + (k0 << 5) + 4);
                Af[k0].u.x = pk2(a.x, a.y);
                Af[k0].u.y = pk2(a.z, a.w);
                Af[k0].u.z = pk2(b.x, b.y);
                Af[k0].u.w = pk2(b.z, b.w);
            }
        }
    } else {
#pragma unroll
        for (int k0 = 0; k0 < 4; ++k0) Af[k0].u = make_uint4(0, 0, 0, 0);
    }

    f32x4 acc[8];
#pragma unroll
    for (int nt = 0; nt < 8; ++nt) acc[nt] = (f32x4){0.f, 0.f, 0.f, 0.f};

#pragma unroll
    for (int nt = 0; nt < 8; ++nt) {
        union { uint4 u; bf16x8 v; } Bf[4];
        const size_t bbase = ((size_t)(nt * 16 + c) << 7) + (q << 3);
#pragma unroll
        for (int k0 = 0; k0 < 4; ++k0)
            Bf[k0].u = *(const uint4*)(Wb + bbase + (k0 << 5));
#pragma unroll
        for (int k0 = 0; k0 < 4; ++k0)
            acc[nt] = __builtin_amdgcn_mfma_f32_16x16x32_bf16(Af[k0].v, Bf[k0].v, acc[nt], 0, 0, 0);
    }

    // fused AS/AD; C/D layout col=lane&15, row=q*4+reg
    float ps[4] = {0.f, 0.f, 0.f, 0.f}, pd[4] = {0.f, 0.f, 0.f, 0.f};
#pragma unroll
    for (int nt = 0; nt < 8; ++nt) {
        float av = asrc[nt * 16 + c];
        float dv = adst[nt * 16 + c];
#pragma unroll
        for (int r = 0; r < 4; ++r) {
            ps[r] = fmaf(acc[nt][r], av, ps[r]);
            pd[r] = fmaf(acc[nt][r], dv, pd[r]);
        }
    }
#pragma unroll
    for (int m = 1; m < 16; m <<= 1) {
#pragma unroll
        for (int r = 0; r < 4; ++r) { ps[r] += __shfl_xor(ps[r], m); pd[r] += __shfl_xor(pd[r], m); }
    }
    if (c == 0) {
#pragma unroll
        for (int r = 0; r < 4; ++r) {
            int grow = r0 + q * 4 + r;
            if (grow < NN) { AS[grow] = ps[r]; AD[grow] = pd[r]; }
        }
    }

    // H store via LDS transpose, pk-cvt to bf16
#pragma unroll
    for (int nt = 0; nt < 8; ++nt)
#pragma unroll
        for (int r = 0; r < 4; ++r)
            hst[w][q * 4 + r][nt * 16 + c] = acc[nt][r];
    __syncthreads();
    {
        const int orow = lane >> 2, seg = lane & 3;
        const int grow = r0 + orow;
        if (grow < NN) {
#pragma unroll
            for (int i = 0; i < 4; ++i) {
                float4 a = *(const float4*)&hst[w][orow][seg * 32 + i * 8];
                float4 b = *(const float4*)&hst[w][orow][seg * 32 + i * 8 + 4];
                uint4 o;
                o.x = pk2(a.x, a.y); o.y = pk2(a.z, a.w);
                o.z = pk2(b.x, b.y); o.w = pk2(b.z, b.w);
                *(uint4*)(Hb + ((size_t)grow << 7) + seg * 32 + i * 8) = o;
            }
        }
    }
}

// ======================= per-dst softmax + aggregation (single pass) =======================
// exp without max-subtraction: e = leaky(AS+AD) is O(1); softmax shift-invariant; fp32 exp safe.
// Body = round-0 measured-best. OUTBF=1: write bf16 rows (layers 0/1 intermediate) — halves
// the write traffic; verified correctness-neutral in r4 (absmax unchanged).
template<int OUTBF>
__global__ __launch_bounds__(256) void k_agg(
    const int* __restrict__ off, const int* __restrict__ srcs,
    const unsigned short* __restrict__ Hb, const float* __restrict__ AS,
    const float* __restrict__ AD, const float* __restrict__ bias,
    void* __restrict__ OUT)
{
    __shared__ uint2 s_e[4][64];
    const int wid  = threadIdx.x >> 6;
    const int lane = threadIdx.x & 63;
    const int g    = lane >> 4;     // edge subgroup 0..3
    const int x16  = lane & 15;     // 16-lane column group
    const int n    = blockIdx.x * 4 + wid;
    const int beg = off[n], end = off[n + 1];
    const float adn = AD[n];

    float acc[8];
#pragma unroll
    for (int i = 0; i < 8; ++i) acc[i] = 0.f;
    float den = 0.f;

    for (int base = beg; base < end; base += 64) {
        int cnt = end - base; if (cnt > 64) cnt = 64;
        float wgt = 0.f; int s = 0;
        if (lane < cnt) {
            s = srcs[base + lane];
            float e = AS[s] + adn;
            e = (e > 0.f) ? e : 0.2f * e;
            wgt = __expf(e);
        }
        s_e[wid][lane] = make_uint2((unsigned int)s, __builtin_bit_cast(unsigned int, wgt));
        den += wgt;
        int rounds = (cnt + 3) >> 2;
        for (int j = 0; j < rounds; ++j) {
            uint2 ew = s_e[wid][(j << 2) + g];
            float wq = __builtin_bit_cast(float, ew.y);
            uint4 u = *((const uint4*)(Hb + ((size_t)ew.x << 7)) + x16);
            acc[0] = fmaf(wq, bflo(u.x), acc[0]);
            acc[1] = fmaf(wq, bfhi(u.x), acc[1]);
            acc[2] = fmaf(wq, bflo(u.y), acc[2]);
            acc[3] = fmaf(wq, bfhi(u.y), acc[3]);
            acc[4] = fmaf(wq, bflo(u.z), acc[4]);
            acc[5] = fmaf(wq, bfhi(u.z), acc[5]);
            acc[6] = fmaf(wq, bflo(u.w), acc[6]);
            acc[7] = fmaf(wq, bfhi(u.w), acc[7]);
        }
    }

    // reduce partial sums across the 4 edge subgroups; den across all 64 lanes
#pragma unroll
    for (int i = 0; i < 8; ++i) {
        acc[i] += __shfl_xor(acc[i], 16);
        acc[i] += __shfl_xor(acc[i], 32);
    }
#pragma unroll
    for (int o = 32; o; o >>= 1) den += __shfl_xor(den, o);
    float inv = 1.f / den;

    if (g == 0) {
        float4 b1 = *(const float4*)&bias[x16 << 3];
        float4 b2 = *(const float4*)&bias[(x16 << 3) + 4];
        float o0 = fmaf(acc[0], inv, b1.x), o1 = fmaf(acc[1], inv, b1.y);
        float o2 = fmaf(acc[2], inv, b1.z), o3 = fmaf(acc[3], inv, b1.w);
        float o4 = fmaf(acc[4], inv, b2.x), o5 = fmaf(acc[5], inv, b2.y);
        float o6 = fmaf(acc[6], inv, b2.z), o7 = fmaf(acc[7], inv, b2.w);
        if (OUTBF) {
            uint4 pkd;
            pkd.x = pk2(o0, o1); pkd.y = pk2(o2, o3);
            pkd.z = pk2(o4, o5); pkd.w = pk2(o6, o7);
            *(uint4*)((unsigned short*)OUT + ((size_t)n << 7) + (x16 << 3)) = pkd;
        } else {
            float* op = (float*)OUT + ((size_t)n << 7) + (x16 << 3);
            *(float4*)op = make_float4(o0, o1, o2, o3);
            *(float4*)(op + 4) = make_float4(o4, o5, o6, o7);
        }
    }
}

// ======================= batchnorm stats from bf16 rows =======================
// r5 post-mortem: 16-accumulator/uint4 version spilled (VGPR_Count=20 < 16 acc + uint4)
// -> scratch thrash, 83.7us, VALUBusy 1%. This version: 4 accumulators/thread, dword
// loads (1 VGPR each -> deep MLP), one u32 column-pair per thread — the proven old
// fp32-colsum structure adapted to bf16.
__global__ __launch_bounds__(256) void k_colsum(const unsigned int* __restrict__ Xb,
                                                float* __restrict__ gsum, float* __restrict__ gsq) {
    __shared__ float ls[4][128], lq[4][128];
    const int t = threadIdx.x;
    const int c2 = t & 63;      // u32 column index (bf16 cols 2*c2, 2*c2+1)
    const int half = t >> 6;    // 4 rows in parallel per block
    float s0 = 0.f, s1 = 0.f, q0 = 0.f, q1 = 0.f;
    for (int r = blockIdx.x * 4 + half; r < NN; r += STAT_BLOCKS * 4) {
        unsigned int v = Xb[(size_t)r * 64 + c2];
        float f0 = bflo(v), f1 = bfhi(v);
        s0 += f0; q0 += f0 * f0;
        s1 += f1; q1 += f1 * f1;
    }
    ls[half][2 * c2] = s0; ls[half][2 * c2 + 1] = s1;
    lq[half][2 * c2] = q0; lq[half][2 * c2 + 1] = q1;
    __syncthreads();
    if (t < 128) {
        float ss = ls[0][t] + ls[1][t] + ls[2][t] + ls[3][t];
        float qq = lq[0][t] + lq[1][t] + lq[2][t] + lq[3][t];
        atomicAdd(&gsum[t], ss);
        atomicAdd(&gsq[t], qq);
    }
}

extern "C" void kernel_launch(void* const* d_in, const int* in_sizes, int n_in,
                              void* d_out, int out_size, void* d_ws, size_t ws_size,
                              hipStream_t stream)
{
    const float* x  = (const float*)d_in[0];
    const int*   ei = (const int*)d_in[1];
    const float* Wm[3]  = {(const float*)d_in[2], (const float*)d_in[6],  (const float*)d_in[10]};
    const float* Asr[3] = {(const float*)d_in[3], (const float*)d_in[7],  (const float*)d_in[11]};
    const float* Ads[3] = {(const float*)d_in[4], (const float*)d_in[8],  (const float*)d_in[12]};
    const float* Bs[3]  = {(const float*)d_in[5], (const float*)d_in[9],  (const float*)d_in[13]};
    const float* gam[2] = {(const float*)d_in[14], (const float*)d_in[16]};
    const float* bet[2] = {(const float*)d_in[15], (const float*)d_in[17]};

    char* p = (char*)d_ws;
    auto carve = [&](size_t bytes) -> char* {
        char* r = p;
        p += (bytes + 255) & ~(size_t)255;
        return r;
    };
    int*   off_   = (int*)carve((size_t)(NN + 1) * 4);
    int*   srcs   = (int*)carve((size_t)ET * 4);
    unsigned int* bucketed = (unsigned int*)carve((size_t)ET * 4);
    int*   btot   = (int*)carve(256 * 4);          // 1024 B, followed immediately by...
    float* gstat  = (float*)carve(4 * 128 * 4);    // gsum0,gsq0,gsum1,gsq1 (2048 B) — one memset
    int*   bstart = (int*)carve(260 * 4);
    int*   bcur   = (int*)carve(256 * 4);
    unsigned short* Hb  = (unsigned short*)carve((size_t)NP * 128 * 2);
    unsigned short* Wb  = (unsigned short*)carve((size_t)3 * 16384 * 2);  // contiguous 3 layers
    float* AS    = (float*)carve((size_t)NN * 4);
    float* AD    = (float*)carve((size_t)NN * 4);

    float*          OUTf = (float*)d_out;            // final fp32 output
    unsigned short* OUTb = (unsigned short*)d_out;   // bf16 intermediate aliases lower half;
                                                     // layer-N mfma reads it fully BEFORE the
                                                     // next k_agg overwrite (stream order)

    // zero btot + all 4 stat vectors in one shot (they are carved adjacently)
    (void)hipMemsetAsync(btot, 0, 256 * 4 + 4 * 128 * 4, stream);

    // CSR build (bucket sort)
    k_bcount<<<256, 256, 0, stream>>>(ei, btot);
    k_bscan<<<1, 256, 0, stream>>>(btot, bstart, bcur, off_);
    k_bucket<<<(ET + TILE - 1) / TILE, 256, 0, stream>>>(ei, bcur, bucketed);
    k_csr<<<NBKT, 256, 0, stream>>>(bucketed, bstart, off_, srcs);

    // weight conversions (single launch)
    k_cvtw3<<<192, 256, 0, stream>>>(Wm[0], Wm[1], Wm[2], Wb);

    const int MFMA_GRID = NP / 64;

    // layer 0
    k_mfma<0><<<MFMA_GRID, 256, 0, stream>>>(x, Wb, nullptr, nullptr, nullptr, nullptr,
                                             Asr[0], Ads[0], Hb, AS, AD);
    k_agg<1><<<NN / 4, 256, 0, stream>>>(off_, srcs, Hb, AS, AD, Bs[0], OUTb);
    k_colsum<<<STAT_BLOCKS, 256, 0, stream>>>((const unsigned int*)OUTb, gstat, gstat + 128);

    // layer 1 (BN affine computed inside k_mfma from raw sums; bf16 input)
    k_mfma<1><<<MFMA_GRID, 256, 0, stream>>>(OUTb, Wb + 16384, gstat, gstat + 128,
                                             gam[0], bet[0], Asr[1], Ads[1], Hb, AS, AD);
    k_agg<1><<<NN / 4, 256, 0, stream>>>(off_, srcs, Hb, AS, AD, Bs[1], OUTb);
    k_colsum<<<STAT_BLOCKS, 256, 0, stream>>>((const unsigned int*)OUTb, gstat + 256, gstat + 384);

    // layer 2 (final fp32 output into d_out)
    k_mfma<1><<<MFMA_GRID, 256, 0, stream>>>(OUTb, Wb + 32768, gstat + 256, gstat + 384,
                                             gam[1], bet[1], Asr[2], Ads[2], Hb, AS, AD);
    k_agg<0><<<NN / 4, 256, 0, stream>>>(off_, srcs, Hb, AS, AD, Bs[2], OUTf);
}

// Round 7
// 535.042 us; speedup vs baseline: 1.8639x; 1.0511x over previous
//
#include <hip/hip_runtime.h>
#include <cstdint>
#include <cstddef>

#define NN 100000
#define NP 100096          // rows padded to multiple of 64
#define EE 1600000
#define ET 1700000         // EE + NN self-loops
#define NBKT 196           // ceil(NN/512) dst-range buckets
#define TILE 2048          // edges per k_bucket block
#define STAT_BLOCKS 400

typedef short  bf16x8 __attribute__((ext_vector_type(8)));
typedef float  f32x4  __attribute__((ext_vector_type(4)));

__device__ __forceinline__ unsigned short f2bf(float f) {
    unsigned int x = __builtin_bit_cast(unsigned int, f);
    x += 0x7FFFu + ((x >> 16) & 1u);   // RNE
    return (unsigned short)(x >> 16);
}
__device__ __forceinline__ unsigned int pk2(float lo, float hi) {
    return ((unsigned int)f2bf(hi) << 16) | (unsigned int)f2bf(lo);
}
__device__ __forceinline__ float bflo(unsigned int u) {
    return __builtin_bit_cast(float, u << 16);
}
__device__ __forceinline__ float bfhi(unsigned int u) {
    return __builtin_bit_cast(float, u & 0xFFFF0000u);
}
// permuted H layout: stored pos j <-> orig col ((j&7)<<4)|(j>>3)  (j = c*8+nt, col = nt*16+c)
__device__ __forceinline__ int unperm(int j) { return ((j & 7) << 4) | (j >> 3); }

// ======================= CSR build via 2-level bucket sort =======================
// bucket = dst >> 9 (512 dsts per bucket); packed edge = (dst&511)<<17 | src
// NOTE (r4): cooperative fusion of these phases regressed 6x (grid.sync ~90us/sync).

__global__ void k_bcount(const int* __restrict__ ei, int* __restrict__ btot) {
    __shared__ int h[256];
    int t = threadIdx.x;
    h[t] = 0;
    __syncthreads();
    for (int e = blockIdx.x * 256 + t; e < ET; e += 256 * 256) {
        int d = (e < EE) ? ei[EE + e] : (e - EE);
        atomicAdd(&h[d >> 9], 1);
    }
    __syncthreads();
    if (h[t]) atomicAdd(&btot[t], h[t]);
}

__global__ void k_bscan(const int* __restrict__ btot, int* __restrict__ bstart,
                        int* __restrict__ bcur, int* __restrict__ off) {
    __shared__ int s[256];
    int t = threadIdx.x;
    int v = (t < NBKT) ? btot[t] : 0;
    s[t] = v;
    __syncthreads();
    for (int o = 1; o < 256; o <<= 1) {
        int a = (t >= o) ? s[t - o] : 0;
        __syncthreads();
        s[t] += a;
        __syncthreads();
    }
    int ex = s[t] - v;
    if (t <= NBKT) bstart[t] = (t < NBKT) ? ex : ET;
    if (t == NBKT - 1) bstart[NBKT] = s[t];   // == ET
    bcur[t] = ex;
    if (t == 0) off[NN] = ET;
}

__global__ __launch_bounds__(256) void k_bucket(
    const int* __restrict__ ei, int* __restrict__ bcur, unsigned int* __restrict__ bucketed)
{
    __shared__ int h4[4][256], woff[4][256], loff[256], gbase[256], sc[256];
    __shared__ unsigned int stage[TILE];
    __shared__ int gaddr[TILE];
    __shared__ int stot_s;
    const int t = threadIdx.x;
    const int w = t >> 6;
    const int e0 = blockIdx.x * TILE;

    h4[0][t] = 0; h4[1][t] = 0; h4[2][t] = 0; h4[3][t] = 0;
    __syncthreads();

    unsigned int pk[TILE / 256];
    int bk[TILE / 256];
#pragma unroll
    for (int i = 0; i < TILE / 256; ++i) {
        int e = e0 + i * 256 + t;
        bk[i] = -1;
        if (e < ET) {
            int s, d;
            if (e < EE) { s = ei[e]; d = ei[EE + e]; } else { s = e - EE; d = s; }
            bk[i] = d >> 9;
            pk[i] = ((unsigned int)(d & 511) << 17) | (unsigned int)s;
            atomicAdd(&h4[w][bk[i]], 1);
        }
    }
    __syncthreads();

    // per-bucket totals + inclusive scan
    int h0 = h4[0][t], h1 = h4[1][t], h2 = h4[2][t], h3 = h4[3][t];
    int tot = h0 + h1 + h2 + h3;
    sc[t] = tot;
    __syncthreads();
    for (int o = 1; o < 256; o <<= 1) {
        int a = (t >= o) ? sc[t - o] : 0;
        __syncthreads();
        sc[t] += a;
        __syncthreads();
    }
    int lo = sc[t] - tot;
    loff[t] = lo;
    woff[0][t] = lo;
    woff[1][t] = lo + h0;
    woff[2][t] = lo + h0 + h1;
    woff[3][t] = lo + h0 + h1 + h2;
    if (t < NBKT && tot) gbase[t] = atomicAdd(&bcur[t], tot);
    if (t == 255) stot_s = sc[255];
    h4[0][t] = 0; h4[1][t] = 0; h4[2][t] = 0; h4[3][t] = 0;
    __syncthreads();

    // rank (per-wave counters -> 4x less LDS-atomic contention) + stage
#pragma unroll
    for (int i = 0; i < TILE / 256; ++i) {
        if (bk[i] >= 0) {
            int b = bk[i];
            int r = woff[w][b] + atomicAdd(&h4[w][b], 1);
            stage[r] = pk[i];
            gaddr[r] = gbase[b] + (r - loff[b]);
        }
    }
    __syncthreads();

    const int stot = stot_s;
    for (int j = t; j < stot; j += 256)
        bucketed[gaddr[j]] = stage[j];
}

__global__ __launch_bounds__(256) void k_csr(
    const unsigned int* __restrict__ bucketed, const int* __restrict__ bstart,
    int* __restrict__ off, int* __restrict__ srcs)
{
    __shared__ int h[512], sc2[512], c2[512], sp[256];
    const int t = threadIdx.x;
    const int b = blockIdx.x;
    const int beg = bstart[b], end = bstart[b + 1];
    const int cnt = end - beg;

    h[t] = 0; h[t + 256] = 0; c2[t] = 0; c2[t + 256] = 0;
    __syncthreads();
    for (int i = t; i < cnt; i += 256)
        atomicAdd(&h[bucketed[beg + i] >> 17], 1);
    __syncthreads();

    int a0 = h[2 * t], a1 = h[2 * t + 1];
    sp[t] = a0 + a1;
    __syncthreads();
    for (int o = 1; o < 256; o <<= 1) {
        int a = (t >= o) ? sp[t - o] : 0;
        __syncthreads();
        sp[t] += a;
        __syncthreads();
    }
    int ep = sp[t] - (a0 + a1);
    sc2[2 * t] = ep;
    sc2[2 * t + 1] = ep + a0;
    __syncthreads();

    const int d0 = b << 9;
#pragma unroll
    for (int k = t; k < 512; k += 256) {
        int d = d0 + k;
        if (d < NN) off[d] = beg + sc2[k];
    }

    for (int i = t; i < cnt; i += 256) {
        unsigned int v = bucketed[beg + i];
        int ld = v >> 17;
        int r = atomicAdd(&c2[ld], 1);
        srcs[beg + sc2[ld] + r] = (int)(v & 0x1FFFFu);
    }
}

// ======================= weight conversion (all 3 layers, one launch) =======================
// layers 1,2 consume permuted H -> permute their k-dim to match (dot product invariant)
__global__ void k_cvtw3(const float* __restrict__ W0, const float* __restrict__ W1,
                        const float* __restrict__ W2, unsigned short* __restrict__ Wb) {
    int i = blockIdx.x * 256 + threadIdx.x;   // 49152 elements
    int layer = i >> 14;
    const float* W = (layer == 0) ? W0 : (layer == 1) ? W1 : W2;
    int base = i & 16383;
    int src = (layer == 0) ? base : ((base & ~127) | unperm(base & 127));
    Wb[i] = f2bf(W[src]);
}

// ======================= MFMA GEMM: H = X @ W^T, fused BN-affine/relu/cvt + AS/AD ===========
// MODE 0: fp32 X read (layer 0); MODE 1: permuted-bf16 X read + BN affine + relu.
// r6 change: Hb stored DIRECTLY from acc in permuted layout (j=c*8+nt) — kills the
// 33.8KB LDS transpose epilogue (32 ds_write + 8 ds_read_b128 + sync per thread) that
// made this kernel VALU-bound, and unlocks occupancy (LDS 35KB -> 1KB).
template<int MODE>
__global__ __launch_bounds__(256) void k_mfma(
    const void* __restrict__ Xv, const unsigned short* __restrict__ Wb,
    const float* __restrict__ gsum, const float* __restrict__ gsq,
    const float* __restrict__ gamma, const float* __restrict__ beta,
    const float* __restrict__ asrc, const float* __restrict__ adst,
    unsigned short* __restrict__ Hb, float* __restrict__ AS, float* __restrict__ AD)
{
    __shared__ float scale_s[128], shift_s[128];
    const int t    = threadIdx.x;
    const int lane = t & 63;
    const int c    = lane & 15;
    const int q    = lane >> 4;
    const int r0   = blockIdx.x * 64 + (t >> 6) * 16;
    const int row  = r0 + c;

    if (MODE) {
        // BN affine from raw sums; stats arrive in PERMUTED order (gstat[t] = col unperm(t)),
        // so gamma/beta are fetched at unperm(t) and scale_s stays in permuted (A) order.
        if (t < 128) {
            int ot = unperm(t);
            float mu  = gsum[t] * (1.f / NN);
            float var = gsq[t] * (1.f / NN) - mu * mu;
            float sc  = gamma[ot] * rsqrtf(var + 1e-5f);
            scale_s[t] = sc;
            shift_s[t] = beta[ot] - mu * sc;
        }
        __syncthreads();
    }

    union { uint4 u; bf16x8 v; } Af[4];
    if (row < NN) {
        if (MODE) {
            const unsigned short* xp = (const unsigned short*)Xv + ((size_t)row << 7) + (q << 3);
#pragma unroll
            for (int k0 = 0; k0 < 4; ++k0) {
                uint4 r = *(const uint4*)(xp + (k0 << 5));
                const int kb = (k0 << 5) + (q << 3);
                float a0 = bflo(r.x), a1 = bfhi(r.x), a2 = bflo(r.y), a3 = bfhi(r.y);
                float a4 = bflo(r.z), a5 = bfhi(r.z), a6 = bflo(r.w), a7 = bfhi(r.w);
                float4 sA = *(const float4*)&scale_s[kb];
                float4 sB = *(const float4*)&scale_s[kb + 4];
                float4 hA = *(const float4*)&shift_s[kb];
                float4 hB = *(const float4*)&shift_s[kb + 4];
                a0 = fmaxf(0.f, fmaf(a0, sA.x, hA.x));
                a1 = fmaxf(0.f, fmaf(a1, sA.y, hA.y));
                a2 = fmaxf(0.f, fmaf(a2, sA.z, hA.z));
                a3 = fmaxf(0.f, fmaf(a3, sA.w, hA.w));
                a4 = fmaxf(0.f, fmaf(a4, sB.x, hB.x));
                a5 = fmaxf(0.f, fmaf(a5, sB.y, hB.y));
                a6 = fmaxf(0.f, fmaf(a6, sB.z, hB.z));
                a7 = fmaxf(0.f, fmaf(a7, sB.w, hB.w));
                Af[k0].u.x = pk2(a0, a1);
                Af[k0].u.y = pk2(a2, a3);
                Af[k0].u.z = pk2(a4, a5);
                Af[k0].u.w = pk2(a6, a7);
            }
        } else {
            const float* xp = (const float*)Xv + ((size_t)row << 7) + (q << 3);
#pragma unroll
            for (int k0 = 0; k0 < 4; ++k0) {
                float4 a = *(const float4*)(xp + (k0 << 5));
                float4 b = *(const float4*)(xp + (k0 << 5) + 4);
                Af[k0].u.x = pk2(a.x, a.y);
                Af[k0].u.y = pk2(a.z, a.w);
                Af[k0].u.z = pk2(b.x, b.y);
                Af[k0].u.w = pk2(b.z, b.w);
            }
        }
    } else {
#pragma unroll
        for (int k0 = 0; k0 < 4; ++k0) Af[k0].u = make_uint4(0, 0, 0, 0);
    }

    f32x4 acc[8];
#pragma unroll
    for (int nt = 0; nt < 8; ++nt) acc[nt] = (f32x4){0.f, 0.f, 0.f, 0.f};

#pragma unroll
    for (int nt = 0; nt < 8; ++nt) {
        union { uint4 u; bf16x8 v; } Bf[4];
        const size_t bbase = ((size_t)(nt * 16 + c) << 7) + (q << 3);
#pragma unroll
        for (int k0 = 0; k0 < 4; ++k0)
            Bf[k0].u = *(const uint4*)(Wb + bbase + (k0 << 5));
#pragma unroll
        for (int k0 = 0; k0 < 4; ++k0)
            acc[nt] = __builtin_amdgcn_mfma_f32_16x16x32_bf16(Af[k0].v, Bf[k0].v, acc[nt], 0, 0, 0);
    }

    // fused AS/AD; C/D layout col=lane&15, row=q*4+reg (orig col order -> asrc standard)
    float ps[4] = {0.f, 0.f, 0.f, 0.f}, pd[4] = {0.f, 0.f, 0.f, 0.f};
#pragma unroll
    for (int nt = 0; nt < 8; ++nt) {
        float av = asrc[nt * 16 + c];
        float dv = adst[nt * 16 + c];
#pragma unroll
        for (int r = 0; r < 4; ++r) {
            ps[r] = fmaf(acc[nt][r], av, ps[r]);
            pd[r] = fmaf(acc[nt][r], dv, pd[r]);
        }
    }
#pragma unroll
    for (int m = 1; m < 16; m <<= 1) {
#pragma unroll
        for (int r = 0; r < 4; ++r) { ps[r] += __shfl_xor(ps[r], m); pd[r] += __shfl_xor(pd[r], m); }
    }
    if (c == 0) {
#pragma unroll
        for (int r = 0; r < 4; ++r) {
            int grow = r0 + q * 4 + r;
            if (grow < NN) { AS[grow] = ps[r]; AD[grow] = pd[r]; }
        }
    }

    // direct permuted Hb store: lane writes its 8 nt-values as one uint4 per row.
    // 16 c-lanes per (q,r) cover 256B contiguous -> fully coalesced.
#pragma unroll
    for (int r = 0; r < 4; ++r) {
        int grow = r0 + q * 4 + r;
        if (grow < NN) {
            uint4 o;
            o.x = pk2(acc[0][r], acc[1][r]);
            o.y = pk2(acc[2][r], acc[3][r]);
            o.z = pk2(acc[4][r], acc[5][r]);
            o.w = pk2(acc[6][r], acc[7][r]);
            *(uint4*)(Hb + ((size_t)grow << 7) + (c << 3)) = o;
        }
    }
}

// ======================= per-dst softmax + aggregation (single pass) =======================
// exp without max-subtraction (softmax shift-invariant; fp32 exp safe for this model).
// H rows arrive permuted: stored j = x16*8+i  <->  orig col i*16+x16.
// OUTBF=1: keep permuted order (bias fetched permuted). OUTBF=0: unpermute on final
// fp32 write (8 lane-coalesced 64B stores).
template<int OUTBF>
__global__ __launch_bounds__(256) void k_agg(
    const int* __restrict__ off, const int* __restrict__ srcs,
    const unsigned short* __restrict__ Hb, const float* __restrict__ AS,
    const float* __restrict__ AD, const float* __restrict__ bias,
    void* __restrict__ OUT)
{
    __shared__ uint2 s_e[4][64];
    const int wid  = threadIdx.x >> 6;
    const int lane = threadIdx.x & 63;
    const int g    = lane >> 4;     // edge subgroup 0..3
    const int x16  = lane & 15;     // 16-lane column group
    const int n    = blockIdx.x * 4 + wid;
    const int beg = off[n], end = off[n + 1];
    const float adn = AD[n];

    float acc[8];
#pragma unroll
    for (int i = 0; i < 8; ++i) acc[i] = 0.f;
    float den = 0.f;

    for (int base = beg; base < end; base += 64) {
        int cnt = end - base; if (cnt > 64) cnt = 64;
        float wgt = 0.f; int s = 0;
        if (lane < cnt) {
            s = srcs[base + lane];
            float e = AS[s] + adn;
            e = (e > 0.f) ? e : 0.2f * e;
            wgt = __expf(e);
        }
        s_e[wid][lane] = make_uint2((unsigned int)s, __builtin_bit_cast(unsigned int, wgt));
        den += wgt;
        int rounds = (cnt + 3) >> 2;
        for (int j = 0; j < rounds; ++j) {
            uint2 ew = s_e[wid][(j << 2) + g];
            float wq = __builtin_bit_cast(float, ew.y);
            uint4 u = *((const uint4*)(Hb + ((size_t)ew.x << 7)) + x16);
            acc[0] = fmaf(wq, bflo(u.x), acc[0]);
            acc[1] = fmaf(wq, bfhi(u.x), acc[1]);
            acc[2] = fmaf(wq, bflo(u.y), acc[2]);
            acc[3] = fmaf(wq, bfhi(u.y), acc[3]);
            acc[4] = fmaf(wq, bflo(u.z), acc[4]);
            acc[5] = fmaf(wq, bfhi(u.z), acc[5]);
            acc[6] = fmaf(wq, bflo(u.w), acc[6]);
            acc[7] = fmaf(wq, bfhi(u.w), acc[7]);
        }
    }

    // reduce partial sums across the 4 edge subgroups; den across all 64 lanes
#pragma unroll
    for (int i = 0; i < 8; ++i) {
        acc[i] += __shfl_xor(acc[i], 16);
        acc[i] += __shfl_xor(acc[i], 32);
    }
#pragma unroll
    for (int o = 32; o; o >>= 1) den += __shfl_xor(den, o);
    float inv = 1.f / den;

    if (g == 0) {
        // acc[i] corresponds to orig col i*16+x16
        float o8[8];
#pragma unroll
        for (int i = 0; i < 8; ++i)
            o8[i] = fmaf(acc[i], inv, bias[i * 16 + x16]);
        if (OUTBF) {
            uint4 pkd;
            pkd.x = pk2(o8[0], o8[1]); pkd.y = pk2(o8[2], o8[3]);
            pkd.z = pk2(o8[4], o8[5]); pkd.w = pk2(o8[6], o8[7]);
            *(uint4*)((unsigned short*)OUT + ((size_t)n << 7) + (x16 << 3)) = pkd;
        } else {
            float* op = (float*)OUT + ((size_t)n << 7) + x16;
#pragma unroll
            for (int i = 0; i < 8; ++i)
                op[i * 16] = o8[i];    // 16 lanes x fixed i = 64B coalesced line
        }
    }
}

// ======================= batchnorm stats from bf16 rows (permuted order — consistent) ======
// r5 lesson: keep 4 accumulators/thread + dword loads (16-acc/uint4 version spilled).
__global__ __launch_bounds__(256) void k_colsum(const unsigned int* __restrict__ Xb,
                                                float* __restrict__ gsum, float* __restrict__ gsq) {
    __shared__ float ls[4][128], lq[4][128];
    const int t = threadIdx.x;
    const int c2 = t & 63;      // u32 column index (stored bf16 cols 2*c2, 2*c2+1)
    const int half = t >> 6;    // 4 rows in parallel per block
    float s0 = 0.f, s1 = 0.f, q0 = 0.f, q1 = 0.f;
    for (int r = blockIdx.x * 4 + half; r < NN; r += STAT_BLOCKS * 4) {
        unsigned int v = Xb[(size_t)r * 64 + c2];
        float f0 = bflo(v), f1 = bfhi(v);
        s0 += f0; q0 += f0 * f0;
        s1 += f1; q1 += f1 * f1;
    }
    ls[half][2 * c2] = s0; ls[half][2 * c2 + 1] = s1;
    lq[half][2 * c2] = q0; lq[half][2 * c2 + 1] = q1;
    __syncthreads();
    if (t < 128) {
        float ss = ls[0][t] + ls[1][t] + ls[2][t] + ls[3][t];
        float qq = lq[0][t] + lq[1][t] + lq[2][t] + lq[3][t];
        atomicAdd(&gsum[t], ss);
        atomicAdd(&gsq[t], qq);
    }
}

extern "C" void kernel_launch(void* const* d_in, const int* in_sizes, int n_in,
                              void* d_out, int out_size, void* d_ws, size_t ws_size,
                              hipStream_t stream)
{
    const float* x  = (const float*)d_in[0];
    const int*   ei = (const int*)d_in[1];
    const float* Wm[3]  = {(const float*)d_in[2], (const float*)d_in[6],  (const float*)d_in[10]};
    const float* Asr[3] = {(const float*)d_in[3], (const float*)d_in[7],  (const float*)d_in[11]};
    const float* Ads[3] = {(const float*)d_in[4], (const float*)d_in[8],  (const float*)d_in[12]};
    const float* Bs[3]  = {(const float*)d_in[5], (const float*)d_in[9],  (const float*)d_in[13]};
    const float* gam[2] = {(const float*)d_in[14], (const float*)d_in[16]};
    const float* bet[2] = {(const float*)d_in[15], (const float*)d_in[17]};

    char* p = (char*)d_ws;
    auto carve = [&](size_t bytes) -> char* {
        char* r = p;
        p += (bytes + 255) & ~(size_t)255;
        return r;
    };
    int*   off_   = (int*)carve((size_t)(NN + 1) * 4);
    int*   srcs   = (int*)carve((size_t)ET * 4);
    unsigned int* bucketed = (unsigned int*)carve((size_t)ET * 4);
    int*   btot   = (int*)carve(256 * 4);          // 1024 B, followed immediately by...
    float* gstat  = (float*)carve(4 * 128 * 4);    // gsum0,gsq0,gsum1,gsq1 (2048 B) — one memset
    int*   bstart = (int*)carve(260 * 4);
    int*   bcur   = (int*)carve(256 * 4);
    unsigned short* Hb  = (unsigned short*)carve((size_t)NP * 128 * 2);
    unsigned short* Wb  = (unsigned short*)carve((size_t)3 * 16384 * 2);  // contiguous 3 layers
    float* AS    = (float*)carve((size_t)NN * 4);
    float* AD    = (float*)carve((size_t)NN * 4);

    float*          OUTf = (float*)d_out;            // final fp32 output
    unsigned short* OUTb = (unsigned short*)d_out;   // bf16 intermediate aliases lower half;
                                                     // layer-N mfma reads it fully BEFORE the
                                                     // next k_agg overwrite (stream order)

    // zero btot + all 4 stat vectors in one shot (they are carved adjacently)
    (void)hipMemsetAsync(btot, 0, 256 * 4 + 4 * 128 * 4, stream);

    // CSR build (bucket sort)
    k_bcount<<<256, 256, 0, stream>>>(ei, btot);
    k_bscan<<<1, 256, 0, stream>>>(btot, bstart, bcur, off_);
    k_bucket<<<(ET + TILE - 1) / TILE, 256, 0, stream>>>(ei, bcur, bucketed);
    k_csr<<<NBKT, 256, 0, stream>>>(bucketed, bstart, off_, srcs);

    // weight conversions (single launch; W1/W2 k-dim permuted to match H layout)
    k_cvtw3<<<192, 256, 0, stream>>>(Wm[0], Wm[1], Wm[2], Wb);

    const int MFMA_GRID = NP / 64;

    // layer 0
    k_mfma<0><<<MFMA_GRID, 256, 0, stream>>>(x, Wb, nullptr, nullptr, nullptr, nullptr,
                                             Asr[0], Ads[0], Hb, AS, AD);
    k_agg<1><<<NN / 4, 256, 0, stream>>>(off_, srcs, Hb, AS, AD, Bs[0], OUTb);
    k_colsum<<<STAT_BLOCKS, 256, 0, stream>>>((const unsigned int*)OUTb, gstat, gstat + 128);

    // layer 1 (BN affine computed inside k_mfma from raw permuted stats; permuted bf16 input)
    k_mfma<1><<<MFMA_GRID, 256, 0, stream>>>(OUTb, Wb + 16384, gstat, gstat + 128,
                                             gam[0], bet[0], Asr[1], Ads[1], Hb, AS, AD);
    k_agg<1><<<NN / 4, 256, 0, stream>>>(off_, srcs, Hb, AS, AD, Bs[1], OUTb);
    k_colsum<<<STAT_BLOCKS, 256, 0, stream>>>((const unsigned int*)OUTb, gstat + 256, gstat + 384);

    // layer 2 (final fp32 output into d_out, unpermuted on write)
    k_mfma<1><<<MFMA_GRID, 256, 0, stream>>>(OUTb, Wb + 32768, gstat + 256, gstat + 384,
                                             gam[1], bet[1], Asr[2], Ads[2], Hb, AS, AD);
    k_agg<0><<<NN / 4, 256, 0, stream>>>(off_, srcs, Hb, AS, AD, Bs[2], OUTf);
}

// Round 8
// 487.375 us; speedup vs baseline: 2.0462x; 1.0978x over previous
//
#include <hip/hip_runtime.h>
#include <cstdint>
#include <cstddef>

#define NN 100000
#define NP 100096          // rows padded to multiple of 64
#define EE 1600000
#define ET 1700000         // EE + NN self-loops
#define NBKT 196           // ceil(NN/512) dst-range buckets
#define TILE 2048          // edges per k_bucket block
#define NSLOT 8            // striped BN-stat accumulators (atomic contention /8)

typedef short  bf16x8 __attribute__((ext_vector_type(8)));
typedef float  f32x4  __attribute__((ext_vector_type(4)));

__device__ __forceinline__ unsigned short f2bf(float f) {
    unsigned int x = __builtin_bit_cast(unsigned int, f);
    x += 0x7FFFu + ((x >> 16) & 1u);   // RNE
    return (unsigned short)(x >> 16);
}
__device__ __forceinline__ unsigned int pk2(float lo, float hi) {
    return ((unsigned int)f2bf(hi) << 16) | (unsigned int)f2bf(lo);
}
__device__ __forceinline__ float bflo(unsigned int u) {
    return __builtin_bit_cast(float, u << 16);
}
__device__ __forceinline__ float bfhi(unsigned int u) {
    return __builtin_bit_cast(float, u & 0xFFFF0000u);
}
// permuted H layout: stored pos j <-> orig col ((j&7)<<4)|(j>>3)  (j = c*8+nt, col = nt*16+c)
__device__ __forceinline__ int unperm(int j) { return ((j & 7) << 4) | (j >> 3); }

// ======================= fused bcount + weight cvt (independent work, one launch) ==========
// blocks 0..255: dst-bucket histogram.  blocks 256..447: weight conversion into
// FRAGMENT-MAJOR layout WbT[(nt*4+k0)*64 + lane] so k_mfma's B-loads are lane-coalesced
// (r7 post-mortem: row-major B-fragments scatter 64 lanes over 32 cache lines/instr).
__global__ void k_pre(const int* __restrict__ ei,
                      const float* __restrict__ W0, const float* __restrict__ W1,
                      const float* __restrict__ W2, unsigned short* __restrict__ Wb,
                      int* __restrict__ btot)
{
    const int t = threadIdx.x;
    const int b = blockIdx.x;
    if (b < 256) {
        __shared__ int h[256];
        h[t] = 0;
        __syncthreads();
        for (int e = b * 256 + t; e < ET; e += 256 * 256) {
            int d = (e < EE) ? ei[EE + e] : (e - EE);
            atomicAdd(&h[d >> 9], 1);
        }
        __syncthreads();
        if (h[t]) atomicAdd(&btot[t], h[t]);
    } else {
        int i = (b - 256) * 256 + t;       // 0..49151
        int layer = i >> 14;
        const float* W = (layer == 0) ? W0 : (layer == 1) ? W1 : W2;
        int o  = i & 16383;
        int f  = o >> 3, e = o & 7;
        int nt = f >> 8, k0 = (f >> 6) & 3, lane = f & 63;
        int c  = lane & 15, q = lane >> 4;
        int k  = k0 * 32 + q * 8 + e;          // logical k index of A-fragment elem
        int col = (layer == 0) ? k : unperm(k); // layers 1/2 consume permuted H
        Wb[i] = f2bf(W[(nt * 16 + c) * 128 + col]);
    }
}

__global__ void k_bscan(const int* __restrict__ btot, int* __restrict__ bstart,
                        int* __restrict__ bcur, int* __restrict__ off) {
    __shared__ int s[256];
    int t = threadIdx.x;
    int v = (t < NBKT) ? btot[t] : 0;
    s[t] = v;
    __syncthreads();
    for (int o = 1; o < 256; o <<= 1) {
        int a = (t >= o) ? s[t - o] : 0;
        __syncthreads();
        s[t] += a;
        __syncthreads();
    }
    int ex = s[t] - v;
    if (t <= NBKT) bstart[t] = (t < NBKT) ? ex : ET;
    if (t == NBKT - 1) bstart[NBKT] = s[t];   // == ET
    bcur[t] = ex;
    if (t == 0) off[NN] = ET;
}

__global__ __launch_bounds__(256) void k_bucket(
    const int* __restrict__ ei, int* __restrict__ bcur, unsigned int* __restrict__ bucketed)
{
    __shared__ int h4[4][256], woff[4][256], loff[256], gbase[256], sc[256];
    __shared__ unsigned int stage[TILE];
    __shared__ int gaddr[TILE];
    __shared__ int stot_s;
    const int t = threadIdx.x;
    const int w = t >> 6;
    const int e0 = blockIdx.x * TILE;

    h4[0][t] = 0; h4[1][t] = 0; h4[2][t] = 0; h4[3][t] = 0;
    __syncthreads();

    unsigned int pk[TILE / 256];
    int bk[TILE / 256];
#pragma unroll
    for (int i = 0; i < TILE / 256; ++i) {
        int e = e0 + i * 256 + t;
        bk[i] = -1;
        if (e < ET) {
            int s, d;
            if (e < EE) { s = ei[e]; d = ei[EE + e]; } else { s = e - EE; d = s; }
            bk[i] = d >> 9;
            pk[i] = ((unsigned int)(d & 511) << 17) | (unsigned int)s;
            atomicAdd(&h4[w][bk[i]], 1);
        }
    }
    __syncthreads();

    int h0 = h4[0][t], h1 = h4[1][t], h2 = h4[2][t], h3 = h4[3][t];
    int tot = h0 + h1 + h2 + h3;
    sc[t] = tot;
    __syncthreads();
    for (int o = 1; o < 256; o <<= 1) {
        int a = (t >= o) ? sc[t - o] : 0;
        __syncthreads();
        sc[t] += a;
        __syncthreads();
    }
    int lo = sc[t] - tot;
    loff[t] = lo;
    woff[0][t] = lo;
    woff[1][t] = lo + h0;
    woff[2][t] = lo + h0 + h1;
    woff[3][t] = lo + h0 + h1 + h2;
    if (t < NBKT && tot) gbase[t] = atomicAdd(&bcur[t], tot);
    if (t == 255) stot_s = sc[255];
    h4[0][t] = 0; h4[1][t] = 0; h4[2][t] = 0; h4[3][t] = 0;
    __syncthreads();

#pragma unroll
    for (int i = 0; i < TILE / 256; ++i) {
        if (bk[i] >= 0) {
            int b = bk[i];
            int r = woff[w][b] + atomicAdd(&h4[w][b], 1);
            stage[r] = pk[i];
            gaddr[r] = gbase[b] + (r - loff[b]);
        }
    }
    __syncthreads();

    const int stot = stot_s;
    for (int j = t; j < stot; j += 256)
        bucketed[gaddr[j]] = stage[j];
}

__global__ __launch_bounds__(256) void k_csr(
    const unsigned int* __restrict__ bucketed, const int* __restrict__ bstart,
    int* __restrict__ off, int* __restrict__ srcs)
{
    __shared__ int h[512], sc2[512], c2[512], sp[256];
    const int t = threadIdx.x;
    const int b = blockIdx.x;
    const int beg = bstart[b], end = bstart[b + 1];
    const int cnt = end - beg;

    h[t] = 0; h[t + 256] = 0; c2[t] = 0; c2[t + 256] = 0;
    __syncthreads();
    for (int i = t; i < cnt; i += 256)
        atomicAdd(&h[bucketed[beg + i] >> 17], 1);
    __syncthreads();

    int a0 = h[2 * t], a1 = h[2 * t + 1];
    sp[t] = a0 + a1;
    __syncthreads();
    for (int o = 1; o < 256; o <<= 1) {
        int a = (t >= o) ? sp[t - o] : 0;
        __syncthreads();
        sp[t] += a;
        __syncthreads();
    }
    int ep = sp[t] - (a0 + a1);
    sc2[2 * t] = ep;
    sc2[2 * t + 1] = ep + a0;
    __syncthreads();

    const int d0 = b << 9;
#pragma unroll
    for (int k = t; k < 512; k += 256) {
        int d = d0 + k;
        if (d < NN) off[d] = beg + sc2[k];
    }

    for (int i = t; i < cnt; i += 256) {
        unsigned int v = bucketed[beg + i];
        int ld = v >> 17;
        int r = atomicAdd(&c2[ld], 1);
        srcs[beg + sc2[ld] + r] = (int)(v & 0x1FFFFu);
    }
}

// ======================= MFMA GEMM: H = X @ W^T, fused BN-affine/relu/cvt + AS/AD ===========
// MODE 0: fp32 X read (layer 0); MODE 1: permuted-bf16 X read + BN affine (from 8-slot
// striped raw stats) + relu. B-fragments read from fragment-major WbT (lane-coalesced).
template<int MODE>
__global__ __launch_bounds__(256) void k_mfma(
    const void* __restrict__ Xv, const unsigned short* __restrict__ Wb,
    const float* __restrict__ gstat8,
    const float* __restrict__ gamma, const float* __restrict__ beta,
    const float* __restrict__ asrc, const float* __restrict__ adst,
    unsigned short* __restrict__ Hb, float* __restrict__ AS, float* __restrict__ AD)
{
    __shared__ float scale_s[128], shift_s[128];
    const int t    = threadIdx.x;
    const int lane = t & 63;
    const int c    = lane & 15;
    const int q    = lane >> 4;
    const int r0   = blockIdx.x * 64 + (t >> 6) * 16;
    const int row  = r0 + c;

    if (MODE) {
        // BN affine from striped raw sums (stats in PERMUTED/stored col order)
        if (t < 128) {
            float su = 0.f, sq = 0.f;
#pragma unroll
            for (int s = 0; s < NSLOT; ++s) {
                su += gstat8[s * 256 + t];
                sq += gstat8[s * 256 + 128 + t];
            }
            int ot = unperm(t);
            float mu  = su * (1.f / NN);
            float var = sq * (1.f / NN) - mu * mu;
            float sc  = gamma[ot] * rsqrtf(var + 1e-5f);
            scale_s[t] = sc;
            shift_s[t] = beta[ot] - mu * sc;
        }
        __syncthreads();
    }

    union { uint4 u; bf16x8 v; } Af[4];
    if (row < NN) {
        if (MODE) {
            const unsigned short* xp = (const unsigned short*)Xv + ((size_t)row << 7) + (q << 3);
#pragma unroll
            for (int k0 = 0; k0 < 4; ++k0) {
                uint4 r = *(const uint4*)(xp + (k0 << 5));
                const int kb = (k0 << 5) + (q << 3);
                float a0 = bflo(r.x), a1 = bfhi(r.x), a2 = bflo(r.y), a3 = bfhi(r.y);
                float a4 = bflo(r.z), a5 = bfhi(r.z), a6 = bflo(r.w), a7 = bfhi(r.w);
                float4 sA = *(const float4*)&scale_s[kb];
                float4 sB = *(const float4*)&scale_s[kb + 4];
                float4 hA = *(const float4*)&shift_s[kb];
                float4 hB = *(const float4*)&shift_s[kb + 4];
                a0 = fmaxf(0.f, fmaf(a0, sA.x, hA.x));
                a1 = fmaxf(0.f, fmaf(a1, sA.y, hA.y));
                a2 = fmaxf(0.f, fmaf(a2, sA.z, hA.z));
                a3 = fmaxf(0.f, fmaf(a3, sA.w, hA.w));
                a4 = fmaxf(0.f, fmaf(a4, sB.x, hB.x));
                a5 = fmaxf(0.f, fmaf(a5, sB.y, hB.y));
                a6 = fmaxf(0.f, fmaf(a6, sB.z, hB.z));
                a7 = fmaxf(0.f, fmaf(a7, sB.w, hB.w));
                Af[k0].u.x = pk2(a0, a1);
                Af[k0].u.y = pk2(a2, a3);
                Af[k0].u.z = pk2(a4, a5);
                Af[k0].u.w = pk2(a6, a7);
            }
        } else {
            const float* xp = (const float*)Xv + ((size_t)row << 7) + (q << 3);
#pragma unroll
            for (int k0 = 0; k0 < 4; ++k0) {
                float4 a = *(const float4*)(xp + (k0 << 5));
                float4 b = *(const float4*)(xp + (k0 << 5) + 4);
                Af[k0].u.x = pk2(a.x, a.y);
                Af[k0].u.y = pk2(a.z, a.w);
                Af[k0].u.z = pk2(b.x, b.y);
                Af[k0].u.w = pk2(b.z, b.w);
            }
        }
    } else {
#pragma unroll
        for (int k0 = 0; k0 < 4; ++k0) Af[k0].u = make_uint4(0, 0, 0, 0);
    }

    f32x4 acc[8];
#pragma unroll
    for (int nt = 0; nt < 8; ++nt) acc[nt] = (f32x4){0.f, 0.f, 0.f, 0.f};

#pragma unroll
    for (int nt = 0; nt < 8; ++nt) {
        union { uint4 u; bf16x8 v; } Bf[4];
#pragma unroll
        for (int k0 = 0; k0 < 4; ++k0)
            Bf[k0].u = *(const uint4*)(Wb + ((size_t)(((nt << 2) + k0) * 64 + lane) << 3));
#pragma unroll
        for (int k0 = 0; k0 < 4; ++k0)
            acc[nt] = __builtin_amdgcn_mfma_f32_16x16x32_bf16(Af[k0].v, Bf[k0].v, acc[nt], 0, 0, 0);
    }

    // fused AS/AD; C/D layout col=lane&15, row=q*4+reg (orig col order)
    float ps[4] = {0.f, 0.f, 0.f, 0.f}, pd[4] = {0.f, 0.f, 0.f, 0.f};
#pragma unroll
    for (int nt = 0; nt < 8; ++nt) {
        float av = asrc[nt * 16 + c];
        float dv = adst[nt * 16 + c];
#pragma unroll
        for (int r = 0; r < 4; ++r) {
            ps[r] = fmaf(acc[nt][r], av, ps[r]);
            pd[r] = fmaf(acc[nt][r], dv, pd[r]);
        }
    }
#pragma unroll
    for (int m = 1; m < 16; m <<= 1) {
#pragma unroll
        for (int r = 0; r < 4; ++r) { ps[r] += __shfl_xor(ps[r], m); pd[r] += __shfl_xor(pd[r], m); }
    }
    if (c == 0) {
#pragma unroll
        for (int r = 0; r < 4; ++r) {
            int grow = r0 + q * 4 + r;
            if (grow < NN) { AS[grow] = ps[r]; AD[grow] = pd[r]; }
        }
    }

    // direct permuted Hb store (r6): lane writes its 8 nt-values as one uint4 per row
#pragma unroll
    for (int r = 0; r < 4; ++r) {
        int grow = r0 + q * 4 + r;
        if (grow < NN) {
            uint4 o;
            o.x = pk2(acc[0][r], acc[1][r]);
            o.y = pk2(acc[2][r], acc[3][r]);
            o.z = pk2(acc[4][r], acc[5][r]);
            o.w = pk2(acc[6][r], acc[7][r]);
            *(uint4*)(Hb + ((size_t)grow << 7) + (c << 3)) = o;
        }
    }
}

// ======================= per-dst softmax + aggregation (single pass) =======================
// Body = measured-best gather loop. OUTBF=1: bf16 permuted-out + FUSED BN col-stats
// (per-wave row in LDS -> block reduce -> 8-slot striped atomicAdd; replaces k_colsum).
template<int OUTBF>
__global__ __launch_bounds__(256) void k_agg(
    const int* __restrict__ off, const int* __restrict__ srcs,
    const unsigned short* __restrict__ Hb, const float* __restrict__ AS,
    const float* __restrict__ AD, const float* __restrict__ bias,
    void* __restrict__ OUT, float* __restrict__ gstat)
{
    __shared__ uint2 s_e[4][64];
    __shared__ float ssum[4][128], ssq[4][128];
    const int wid  = threadIdx.x >> 6;
    const int lane = threadIdx.x & 63;
    const int g    = lane >> 4;     // edge subgroup 0..3
    const int x16  = lane & 15;     // 16-lane column group
    const int n    = blockIdx.x * 4 + wid;
    const int beg = off[n], end = off[n + 1];
    const float adn = AD[n];

    float acc[8];
#pragma unroll
    for (int i = 0; i < 8; ++i) acc[i] = 0.f;
    float den = 0.f;

    for (int base = beg; base < end; base += 64) {
        int cnt = end - base; if (cnt > 64) cnt = 64;
        float wgt = 0.f; int s = 0;
        if (lane < cnt) {
            s = srcs[base + lane];
            float e = AS[s] + adn;
            e = (e > 0.f) ? e : 0.2f * e;
            wgt = __expf(e);
        }
        s_e[wid][lane] = make_uint2((unsigned int)s, __builtin_bit_cast(unsigned int, wgt));
        den += wgt;
        int rounds = (cnt + 3) >> 2;
        for (int j = 0; j < rounds; ++j) {
            uint2 ew = s_e[wid][(j << 2) + g];
            float wq = __builtin_bit_cast(float, ew.y);
            uint4 u = *((const uint4*)(Hb + ((size_t)ew.x << 7)) + x16);
            acc[0] = fmaf(wq, bflo(u.x), acc[0]);
            acc[1] = fmaf(wq, bfhi(u.x), acc[1]);
            acc[2] = fmaf(wq, bflo(u.y), acc[2]);
            acc[3] = fmaf(wq, bfhi(u.y), acc[3]);
            acc[4] = fmaf(wq, bflo(u.z), acc[4]);
            acc[5] = fmaf(wq, bfhi(u.z), acc[5]);
            acc[6] = fmaf(wq, bflo(u.w), acc[6]);
            acc[7] = fmaf(wq, bfhi(u.w), acc[7]);
        }
    }

#pragma unroll
    for (int i = 0; i < 8; ++i) {
        acc[i] += __shfl_xor(acc[i], 16);
        acc[i] += __shfl_xor(acc[i], 32);
    }
#pragma unroll
    for (int o = 32; o; o >>= 1) den += __shfl_xor(den, o);
    float inv = 1.f / den;

    if (g == 0) {
        // acc[i] corresponds to orig col i*16+x16; stored col j = x16*8+i
        float o8[8];
#pragma unroll
        for (int i = 0; i < 8; ++i)
            o8[i] = fmaf(acc[i], inv, bias[i * 16 + x16]);
        if (OUTBF) {
            uint4 pkd;
            pkd.x = pk2(o8[0], o8[1]); pkd.y = pk2(o8[2], o8[3]);
            pkd.z = pk2(o8[4], o8[5]); pkd.w = pk2(o8[6], o8[7]);
            *(uint4*)((unsigned short*)OUT + ((size_t)n << 7) + (x16 << 3)) = pkd;
#pragma unroll
            for (int i = 0; i < 8; ++i) {
                ssum[wid][(x16 << 3) + i] = o8[i];
                ssq[wid][(x16 << 3) + i]  = o8[i] * o8[i];
            }
        } else {
            float* op = (float*)OUT + ((size_t)n << 7) + x16;
#pragma unroll
            for (int i = 0; i < 8; ++i)
                op[i * 16] = o8[i];    // 16 lanes x fixed i = 64B coalesced line
        }
    }

    if (OUTBF) {
        __syncthreads();
        const int t = threadIdx.x;
        if (t < 128) {
            float ss = ssum[0][t] + ssum[1][t] + ssum[2][t] + ssum[3][t];
            float qq = ssq[0][t] + ssq[1][t] + ssq[2][t] + ssq[3][t];
            float* gs = gstat + (blockIdx.x & (NSLOT - 1)) * 256;
            atomicAdd(&gs[t], ss);
            atomicAdd(&gs[128 + t], qq);
        }
    }
}

extern "C" void kernel_launch(void* const* d_in, const int* in_sizes, int n_in,
                              void* d_out, int out_size, void* d_ws, size_t ws_size,
                              hipStream_t stream)
{
    const float* x  = (const float*)d_in[0];
    const int*   ei = (const int*)d_in[1];
    const float* Wm[3]  = {(const float*)d_in[2], (const float*)d_in[6],  (const float*)d_in[10]};
    const float* Asr[3] = {(const float*)d_in[3], (const float*)d_in[7],  (const float*)d_in[11]};
    const float* Ads[3] = {(const float*)d_in[4], (const float*)d_in[8],  (const float*)d_in[12]};
    const float* Bs[3]  = {(const float*)d_in[5], (const float*)d_in[9],  (const float*)d_in[13]};
    const float* gam[2] = {(const float*)d_in[14], (const float*)d_in[16]};
    const float* bet[2] = {(const float*)d_in[15], (const float*)d_in[17]};

    char* p = (char*)d_ws;
    auto carve = [&](size_t bytes) -> char* {
        char* r = p;
        p += (bytes + 255) & ~(size_t)255;
        return r;
    };
    int*   off_   = (int*)carve((size_t)(NN + 1) * 4);
    int*   srcs   = (int*)carve((size_t)ET * 4);
    unsigned int* bucketed = (unsigned int*)carve((size_t)ET * 4);
    int*   btot   = (int*)carve(256 * 4);                  // 1024 B, then immediately...
    float* gstat  = (float*)carve(2 * NSLOT * 256 * 4);    // 2 layers x 8 slots x 256 (16 KB)
    int*   bstart = (int*)carve(260 * 4);
    int*   bcur   = (int*)carve(256 * 4);
    unsigned short* Hb  = (unsigned short*)carve((size_t)NP * 128 * 2);
    unsigned short* Wb  = (unsigned short*)carve((size_t)3 * 16384 * 2);  // fragment-major
    float* AS    = (float*)carve((size_t)NN * 4);
    float* AD    = (float*)carve((size_t)NN * 4);

    float*          OUTf = (float*)d_out;            // final fp32 output
    unsigned short* OUTb = (unsigned short*)d_out;   // bf16 intermediate aliases lower half

    // zero btot + both layers' striped stats in one shot (adjacent carves)
    (void)hipMemsetAsync(btot, 0, 256 * 4 + 2 * NSLOT * 256 * 4, stream);

    // CSR build (bucket sort) + weight cvt fused into the first kernel
    k_pre<<<448, 256, 0, stream>>>(ei, Wm[0], Wm[1], Wm[2], Wb, btot);
    k_bscan<<<1, 256, 0, stream>>>(btot, bstart, bcur, off_);
    k_bucket<<<(ET + TILE - 1) / TILE, 256, 0, stream>>>(ei, bcur, bucketed);
    k_csr<<<NBKT, 256, 0, stream>>>(bucketed, bstart, off_, srcs);

    const int MFMA_GRID = NP / 64;

    // layer 0
    k_mfma<0><<<MFMA_GRID, 256, 0, stream>>>(x, Wb, nullptr, nullptr, nullptr,
                                             Asr[0], Ads[0], Hb, AS, AD);
    k_agg<1><<<NN / 4, 256, 0, stream>>>(off_, srcs, Hb, AS, AD, Bs[0], OUTb, gstat);

    // layer 1 (BN affine from striped raw stats; permuted bf16 input)
    k_mfma<1><<<MFMA_GRID, 256, 0, stream>>>(OUTb, Wb + 16384, gstat,
                                             gam[0], bet[0], Asr[1], Ads[1], Hb, AS, AD);
    k_agg<1><<<NN / 4, 256, 0, stream>>>(off_, srcs, Hb, AS, AD, Bs[1], OUTb,
                                         gstat + NSLOT * 256);

    // layer 2 (final fp32 output into d_out, unpermuted on write)
    k_mfma<1><<<MFMA_GRID, 256, 0, stream>>>(OUTb, Wb + 32768, gstat + NSLOT * 256,
                                             gam[1], bet[1], Asr[2], Ads[2], Hb, AS, AD);
    k_agg<0><<<NN / 4, 256, 0, stream>>>(off_, srcs, Hb, AS, AD, Bs[2], OUTf, nullptr);
}